// Round 12
// baseline (363.896 us; speedup 1.0000x reference)
//
#include <hip/hip_runtime.h>
#include <math.h>

typedef unsigned short u16;
typedef unsigned int u32;
typedef unsigned long long u64;
typedef __attribute__((ext_vector_type(8))) _Float16 f16x8;
typedef __attribute__((ext_vector_type(2))) _Float16 f16x2;
typedef __attribute__((ext_vector_type(4))) float f32x4;

union U8h { f16x8 v; f16x2 p[4]; u32 u[4]; _Float16 s[8]; };

__device__ __forceinline__ void atomicMaxF(float* addr, float val) {
  if (val >= 0.0f) {
    atomicMax((int*)addr, __float_as_int(val));
  } else {
    atomicMin((unsigned int*)addr, (unsigned int)__float_as_int(val));
  }
}

__device__ __forceinline__ f16x2 pk(float a, float b) {
  return __builtin_bit_cast(f16x2, __builtin_amdgcn_cvt_pkrtz(a, b));
}

// split 8 fp32 -> fp16 hi (RTZ) + lo (residual): hi+lo exact to ~2^-22
__device__ __forceinline__ void dec8h(const float* f, U8h& h, U8h& l) {
#pragma unroll
  for (int i = 0; i < 4; ++i) {
    float a = f[2 * i], b = f[2 * i + 1];
    f16x2 hp = pk(a, b);
    float ra = a - (float)hp[0];
    float rb = b - (float)hp[1];
    h.p[i] = hp;
    l.p[i] = pk(ra, rb);
  }
}

__device__ __forceinline__ void conv8_rne(const float* f, U8h& h) {
#pragma unroll
  for (int i = 0; i < 8; ++i) h.s[i] = (_Float16)f[i];
}

// lane's two 8-float chunks of a 64-float row (cols q*8.. and 32+q*8..)
__device__ __forceinline__ void load_row(const float* p, float* f) {
  *(float4*)(f + 0)  = *(const float4*)(p);
  *(float4*)(f + 4)  = *(const float4*)(p + 4);
  *(float4*)(f + 8)  = *(const float4*)(p + 32);
  *(float4*)(f + 12) = *(const float4*)(p + 36);
}

// ---- cross-q segmented-run merge for dst-sorted scatter-max ----
struct RunCtx { bool chain1, chain2, chain3, suppress; };

__device__ __forceinline__ RunCtx run_ctx(const int dd[4], int lane, int q) {
  bool allsame = (dd[0] == dd[1]) && (dd[1] == dd[2]) && (dd[2] == dd[3]);
  int nfd1 = __shfl(dd[0], lane + 16, 64);
  int nfd2 = __shfl(dd[0], lane + 32, 64);
  int nfd3 = __shfl(dd[0], lane + 48, 64);
  int as = allsame ? 1 : 0;
  int nas1 = __shfl(as, lane + 16, 64);
  int nas2 = __shfl(as, lane + 32, 64);
  int pld = __shfl(dd[3], lane - 16, 64);
  RunCtx c;
  c.chain1 = (q < 3) && (nfd1 == dd[3]);
  c.chain2 = c.chain1 && (nas1 != 0) && (q < 2) && (nfd2 == dd[3]);
  c.chain3 = c.chain2 && (nas2 != 0) && (q < 1) && (nfd3 == dd[3]);
  c.suppress = (q > 0) && (pld == dd[0]);
  return c;
}

__device__ __forceinline__ void emit_t(const f32x4 o, const int dd[4], const RunCtx c,
                                       int lane, int m, int t, float* __restrict__ xnew) {
  float fv = o[0];
  bool c01 = dd[1] == dd[0];
  fv = c01 ? fmaxf(fv, o[1]) : fv;
  bool c012 = c01 && (dd[2] == dd[1]);
  fv = c012 ? fmaxf(fv, o[2]) : fv;
  bool c0123 = c012 && (dd[3] == dd[2]);
  fv = c0123 ? fmaxf(fv, o[3]) : fv;
  float nfv1 = __shfl(fv, lane + 16, 64);
  float nfv2 = __shfl(fv, lane + 32, 64);
  float nfv3 = __shfl(fv, lane + 48, 64);
  float run = o[0];
  bool first = true;
#pragma unroll
  for (int r = 0; r < 4; ++r) {
    if (r > 0) run = (dd[r] == dd[r - 1]) ? fmaxf(run, o[r]) : o[r];
    bool end = (r == 3) || (dd[r + 1] != dd[r]);
    if (end) {
      float val = run;
      if (r == 3) {
        if (c.chain1) val = fmaxf(val, nfv1);
        if (c.chain2) val = fmaxf(val, nfv2);
        if (c.chain3) val = fmaxf(val, nfv3);
      }
      if (!(first && c.suppress) && dd[r] >= 0)
        atomicMaxF(&xnew[(size_t)dd[r] * 64 + t * 16 + m], val);
      first = false;
    }
  }
}

// ---------------- vcp build + degree histogram + goal argmax (fused) ----------------
__global__ __launch_bounds__(256) void k_vch(const float* __restrict__ v,
                                             const float* __restrict__ labels,
                                             float* __restrict__ vcp, int N,
                                             const int* __restrict__ dst, int E,
                                             int* __restrict__ deg, u64* __restrict__ key) {
  int tid = blockIdx.x * 256 + threadIdx.x;
  if (tid < N * 16) {
    int n = tid >> 4, c = tid & 15;
    float val = 0.f;
    if (c < 7) val = v[(size_t)n * 7 + c];
    else if (c == 7) val = labels[2 * (size_t)n];
    else if (c == 8) val = labels[2 * (size_t)n + 1];
    vcp[tid] = val;
  }
  if (tid < E) atomicAdd(&deg[dst[tid]], 1);
  if ((tid & ~63) < N) {
    float val = (tid < N) ? labels[2 * (size_t)tid + 1] : 0.0f;
    u64 k = ((u64)__float_as_uint(fmaxf(val, 0.0f)) << 32) | (u32)(~(u32)tid);
#pragma unroll
    for (int off = 32; off > 0; off >>= 1) {
      u64 o = __shfl_xor(k, off, 64);
      if (o > k) k = o;
    }
    if ((threadIdx.x & 63) == 0) atomicMax(key, k);
  }
}

// ---------------- goal extract + hx goal-folded bias ----------------
__global__ void k_goal2b(const float* __restrict__ v, const float* __restrict__ labels,
                         const u64* __restrict__ key,
                         const float* __restrict__ hxw1, const float* __restrict__ hxb1,
                         float* __restrict__ goal, float* __restrict__ b1p) {
  __shared__ float g[9];
  int gi = (int)(~(u32)(*key));
  int c = threadIdx.x;
  if (c < 9) {
    float gv = (c < 7) ? v[7 * (size_t)gi + c] : labels[2 * (size_t)gi + (c - 7)];
    g[c] = gv;
    goal[c] = gv;
  }
  __syncthreads();
  if (c < 64) {
    float s = hxb1[c];
#pragma unroll
    for (int k = 0; k < 9; ++k) s += g[k] * hxw1[(9 + k) * 64 + c];
    b1p[c] = s;
  }
}

// ---------------- weight prep: frag-major fp16 ----------------
// frag value = Wcat[c*32 + (lane>>4)*8 + j][t*16 + (lane&15)] at ((c*4+t)*64+lane)*8+j
__global__ __launch_bounds__(256) void k_prep(const float* __restrict__ fxw1, const float* __restrict__ fxw2,
                                              const float* __restrict__ fyw1, const float* __restrict__ fyw2,
                                              const float* __restrict__ hyw1, const float* __restrict__ hyw2,
                                              const float* __restrict__ hxw1, const float* __restrict__ hxw2,
                                              const float* __restrict__ few1, const float* __restrict__ few2,
                                              _Float16* __restrict__ wp, u64* __restrict__ goalkey) {
  if (blockIdx.x == 0 && threadIdx.x == 0) *goalkey = 0;
  _Float16* fxB1  = wp;           // 12288 (chunks: 0,1=xs 2,3=xd 4,5=y)
  _Float16* fxB2  = wp + 12288;   // 4096
  _Float16* fyB1  = wp + 16384;   // 8192  (chunks: 0,1=xd 2,3=xs)
  _Float16* fyB2  = wp + 24576;   // 4096
  _Float16* hyB1  = wp + 28672;   // 2048  (K=32: rows 0-15 dst, 16-31 src)
  _Float16* hyB2  = wp + 30720;   // 4096
  _Float16* hxB1  = wp + 34816;   // 2048
  _Float16* hxB2  = wp + 36864;   // 4096
  _Float16* feB1  = wp + 40960;   // 4096
  _Float16* feB2  = wp + 45056;   // 4096
  _Float16* hyB1s = wp + 49152;   // 2048 (src rows remapped to k=0..15)
  int tid = blockIdx.x * 256 + threadIdx.x;
  int which, id;
  _Float16* oh;
  if (tid < 1536)      { which = 0;  id = tid;        oh = fxB1; }
  else if (tid < 2048) { which = 1;  id = tid - 1536; oh = fxB2; }
  else if (tid < 3072) { which = 2;  id = tid - 2048; oh = fyB1; }
  else if (tid < 3584) { which = 3;  id = tid - 3072; oh = fyB2; }
  else if (tid < 3840) { which = 4;  id = tid - 3584; oh = hyB1; }
  else if (tid < 4352) { which = 5;  id = tid - 3840; oh = hyB2; }
  else if (tid < 4608) { which = 6;  id = tid - 4352; oh = hxB1; }
  else if (tid < 5120) { which = 7;  id = tid - 4608; oh = hxB2; }
  else if (tid < 5632) { which = 8;  id = tid - 5120; oh = feB1; }
  else if (tid < 6144) { which = 9;  id = tid - 5632; oh = feB2; }
  else if (tid < 6400) { which = 10; id = tid - 6144; oh = hyB1s; }
  else return;
  int lane = id & 63;
  int q = lane >> 4, col = lane & 15;
  int c = id >> 8, t = (id >> 6) & 3;
#pragma unroll
  for (int j = 0; j < 8; ++j) {
    int k = c * 32 + q * 8 + j;
    int n = t * 16 + col;
    float w;
    if (which == 0) {
      w = (k < 64)  ? fxw1[k * 64 + n] + fxw1[(k + 64) * 64 + n]
        : (k < 128) ? fxw1[(k + 64) * 64 + n] - fxw1[(k - 64) * 64 + n]
                    : fxw1[(k + 64) * 64 + n];
    } else if (which == 1) {
      w = fxw2[k * 64 + n];
    } else if (which == 2) {
      w = (k < 64) ? fyw1[k * 64 + n] + fyw1[(k + 64) * 64 + n]
                   : fyw1[(k + 64) * 64 + n] - fyw1[(k - 64) * 64 + n];
    } else if (which == 3) {
      w = fyw2[k * 64 + n];
    } else if (which == 4) {
      if (k <= 8)                  w = hyw1[k * 64 + n] + hyw1[(k + 9) * 64 + n];
      else if (k >= 16 && k <= 24) w = hyw1[(k + 2) * 64 + n] - hyw1[(k - 16) * 64 + n];
      else                         w = 0.f;
    } else if (which == 5) {
      w = hyw2[k * 64 + n];
    } else if (which == 6) {
      w = (k < 9) ? hxw1[k * 64 + n] : (k < 27) ? hxw1[(k + 9) * 64 + n] : 0.f;
    } else if (which == 7) {
      w = hxw2[k * 64 + n];
    } else if (which == 8) {
      w = few1[k * 64 + n];
    } else if (which == 9) {
      w = few2[k * 64 + n];
    } else {
      // hyB1s: rows 16+k of hy Wcat, remapped to k (k<9 nonzero)
      w = (k < 9) ? hyw1[(k + 18) * 64 + n] - hyw1[k * 64 + n] : 0.f;
    }
    oh[id * 8 + j] = (_Float16)w;
  }
}

// ---------------- CSR scan ----------------
__global__ __launch_bounds__(256) void k_scan1(const int* __restrict__ deg, int N,
                                               int* __restrict__ bsum) {
  __shared__ int red[256];
  int b = blockIdx.x;
  int s = 0;
  for (int i = threadIdx.x; i < 1024; i += 256) {
    int idx = b * 1024 + i;
    s += (idx < N) ? deg[idx] : 0;
  }
  red[threadIdx.x] = s; __syncthreads();
  for (int st = 128; st > 0; st >>= 1) {
    if (threadIdx.x < st) red[threadIdx.x] += red[threadIdx.x + st];
    __syncthreads();
  }
  if (threadIdx.x == 0) bsum[b] = red[0];
}

__global__ __launch_bounds__(256) void k_scan3(const int* __restrict__ deg,
                                               const int* __restrict__ bsum, int N,
                                               int* __restrict__ cursor) {
  __shared__ int lsum[256];
  __shared__ int bofs;
  int b = blockIdx.x;
  int tid = threadIdx.x;
  if (tid == 0) {
    int a = 0;
    for (int i = 0; i < b; ++i) a += bsum[i];
    bofs = a;
  }
  int base_i = b * 1024 + tid * 4;
  int loc[4]; int s = 0;
#pragma unroll
  for (int j = 0; j < 4; ++j) {
    int v = (base_i + j < N) ? deg[base_i + j] : 0;
    loc[j] = s; s += v;
  }
  lsum[tid] = s; __syncthreads();
  for (int st = 1; st < 256; st <<= 1) {
    int add = (tid >= st) ? lsum[tid - st] : 0;
    __syncthreads();
    lsum[tid] += add;
    __syncthreads();
  }
  int toff = bofs + lsum[tid] - s;
#pragma unroll
  for (int j = 0; j < 4; ++j) {
    if (base_i + j < N) cursor[base_i + j] = toff + loc[j];
  }
}

__global__ __launch_bounds__(256) void k_scatter(const int* __restrict__ src,
                                                 const int* __restrict__ dst, int E,
                                                 int* __restrict__ cursor,
                                                 int* __restrict__ srcp, int* __restrict__ dstp) {
  int e = blockIdx.x * 256 + threadIdx.x;
  if (e < E) {
    int d = dst[e];
    int pos = atomicAdd(&cursor[d], 1);
    srcp[pos] = src[e];
    dstp[pos] = d;
  }
}

// ---------------- hx (MFMA): x0 = MLP2([vc; d; d^2] K=32, goal-folded bias) ----------
__global__ __launch_bounds__(256) void k_hx2(
    const float* __restrict__ vcp, const float* __restrict__ goal,
    const _Float16* __restrict__ B1, const float* __restrict__ b1p,
    const _Float16* __restrict__ B2, const float* __restrict__ b2,
    float* __restrict__ xout, float* __restrict__ xout2, int N) {
  __shared__ float hbuf[4][16 * 68];
  const int lane = threadIdx.x & 63;
  const int wv = threadIdx.x >> 6;
  const int m = lane & 15, q = lane >> 4;
  const int base = blockIdx.x * 64 + wv * 16;
  int node = base + m; if (node >= N) node = N - 1;
  float vc[12];
  *(float4*)(vc + 0) = *(const float4*)(vcp + (size_t)node * 16);
  *(float4*)(vc + 4) = *(const float4*)(vcp + (size_t)node * 16 + 4);
  *(float4*)(vc + 8) = *(const float4*)(vcp + (size_t)node * 16 + 8);
  float gl[9];
#pragma unroll
  for (int i = 0; i < 9; ++i) gl[i] = goal[i];
  float f[8];
#pragma unroll
  for (int j = 0; j < 8; ++j) {
    int idx = q * 8 + j;
    float val = 0.f;
    if (idx < 9) val = vc[idx];
    else if (idx < 18) val = vc[idx - 9] - gl[idx - 9];
    else if (idx < 27) { float dv = vc[idx - 18] - gl[idx - 18]; val = dv * dv; }
    f[j] = val;
  }
  U8h Ah, Al;
  dec8h(f, Ah, Al);

  f32x4 acc[4];
#pragma unroll
  for (int t = 0; t < 4; ++t) { float bv = b1p[t * 16 + m]; acc[t] = (f32x4){bv, bv, bv, bv}; }
#pragma unroll
  for (int t = 0; t < 4; ++t) {
    f16x8 b = *(const f16x8*)(B1 + ((size_t)t * 64 + lane) * 8);
    acc[t] = __builtin_amdgcn_mfma_f32_16x16x32_f16(Ah.v, b, acc[t], 0, 0, 0);
    acc[t] = __builtin_amdgcn_mfma_f32_16x16x32_f16(Al.v, b, acc[t], 0, 0, 0);
  }

  float* hb = hbuf[wv];
#pragma unroll
  for (int t = 0; t < 4; ++t)
#pragma unroll
    for (int r = 0; r < 4; ++r)
      hb[(q * 4 + r) * 68 + t * 16 + m] = fmaxf(acc[t][r], 0.f);

  float fh[16];
  load_row(hb + m * 68 + q * 8, fh);
  U8h A2h[2], A2l[2];
  dec8h(fh + 0, A2h[0], A2l[0]);
  dec8h(fh + 8, A2h[1], A2l[1]);

  f32x4 acc2[4];
#pragma unroll
  for (int t = 0; t < 4; ++t) { float bv = b2[t * 16 + m]; acc2[t] = (f32x4){bv, bv, bv, bv}; }
#pragma unroll
  for (int c = 0; c < 2; ++c) {
#pragma unroll
    for (int t = 0; t < 4; ++t) {
      f16x8 b = *(const f16x8*)(B2 + ((size_t)(c * 4 + t) * 64 + lane) * 8);
      acc2[t] = __builtin_amdgcn_mfma_f32_16x16x32_f16(A2h[c].v, b, acc2[t], 0, 0, 0);
      acc2[t] = __builtin_amdgcn_mfma_f32_16x16x32_f16(A2l[c].v, b, acc2[t], 0, 0, 0);
    }
  }

#pragma unroll
  for (int t = 0; t < 4; ++t)
#pragma unroll
    for (int r = 0; r < 4; ++r)
      hb[(q * 4 + r) * 68 + t * 16 + m] = acc2[t][r];

  int row = base + m;
  if (row < N) {
    float ov[16];
    const float* orow = hb + m * 68 + q * 16;
    *(float4*)(ov + 0)  = *(const float4*)(orow);
    *(float4*)(ov + 4)  = *(const float4*)(orow + 4);
    *(float4*)(ov + 8)  = *(const float4*)(orow + 8);
    *(float4*)(ov + 12) = *(const float4*)(orow + 12);
    float* p1 = xout + (size_t)row * 64 + q * 16;
    float* p2 = xout2 + (size_t)row * 64 + q * 16;
#pragma unroll
    for (int i = 0; i < 4; ++i) {
      *(float4*)(p1 + i * 4) = *(const float4*)(ov + i * 4);
      *(float4*)(p2 + i * 4) = *(const float4*)(ov + i * 4);
    }
  }
}

// ---------------- per-node projections ----------------
// P[n][256] fp16 = [B_fy | C_fx | A_fy | D_fx]; src gather = 0..127, dst = 128..255
__global__ __launch_bounds__(256) void k_proj(
    const float* __restrict__ x,
    const _Float16* __restrict__ fyB1, const _Float16* __restrict__ fxB1,
    _Float16* __restrict__ P, float* __restrict__ xcopy, int N) {
  __shared__ float hbuf[4][16 * 68];
  const int lane = threadIdx.x & 63;
  const int wv = threadIdx.x >> 6;
  const int m = lane & 15, q = lane >> 4;
  const int base = blockIdx.x * 64 + wv * 16;
  int node = base + m; if (node >= N) node = N - 1;
  const int row = base + m;
  const bool live = row < N;

  float xr[16];
  load_row(x + (size_t)node * 64 + q * 8, xr);
  U8h X0, X1;
  conv8_rne(xr + 0, X0);
  conv8_rne(xr + 8, X1);
  if (live) {
    float* pc = xcopy + (size_t)row * 64;
    *(float4*)(pc + q * 8)      = *(const float4*)(xr + 0);
    *(float4*)(pc + q * 8 + 4)  = *(const float4*)(xr + 4);
    *(float4*)(pc + 32 + q * 8)     = *(const float4*)(xr + 8);
    *(float4*)(pc + 32 + q * 8 + 4) = *(const float4*)(xr + 12);
  }

  float* hb = hbuf[wv];
#pragma unroll
  for (int p = 0; p < 4; ++p) {
    const _Float16* W = (p == 0 || p == 2) ? fyB1 : fxB1;
    const int c0 = (p == 0 || p == 3) ? 2 : 0;  // B_fy=fy[2,3] C_fx=fx[0,1] A_fy=fy[0,1] D_fx=fx[2,3]
    const int slot = p * 64;
    f32x4 o[4];
#pragma unroll
    for (int t = 0; t < 4; ++t) o[t] = (f32x4){0.f, 0.f, 0.f, 0.f};
#pragma unroll
    for (int t = 0; t < 4; ++t) {
      f16x8 b0 = *(const f16x8*)(W + ((size_t)((c0 + 0) * 4 + t) * 64 + lane) * 8);
      f16x8 b1 = *(const f16x8*)(W + ((size_t)((c0 + 1) * 4 + t) * 64 + lane) * 8);
      o[t] = __builtin_amdgcn_mfma_f32_16x16x32_f16(X0.v, b0, o[t], 0, 0, 0);
      o[t] = __builtin_amdgcn_mfma_f32_16x16x32_f16(X1.v, b1, o[t], 0, 0, 0);
    }
#pragma unroll
    for (int t = 0; t < 4; ++t)
#pragma unroll
      for (int r = 0; r < 4; ++r)
        hb[(q * 4 + r) * 68 + t * 16 + m] = o[t][r];
    float pv[16];
    load_row(hb + m * 68 + q * 8, pv);
    U8h P0, P1;
    conv8_rne(pv + 0, P0);
    conv8_rne(pv + 8, P1);
    if (live) {
      _Float16* pp = P + (size_t)row * 256 + slot;
      *(f16x8*)(pp + q * 8)      = P0.v;
      *(f16x8*)(pp + 32 + q * 8) = P1.v;
    }
  }
}

// t=0 projections: hy parts from vcp (K=16), fx parts from x1
__global__ __launch_bounds__(256) void k_proj0(
    const float* __restrict__ vcp, const float* __restrict__ x,
    const _Float16* __restrict__ hyB1, const _Float16* __restrict__ hyB1s,
    const _Float16* __restrict__ fxB1,
    _Float16* __restrict__ P, int N) {
  __shared__ float hbuf[4][16 * 68];
  const int lane = threadIdx.x & 63;
  const int wv = threadIdx.x >> 6;
  const int m = lane & 15, q = lane >> 4;
  const int base = blockIdx.x * 64 + wv * 16;
  int node = base + m; if (node >= N) node = N - 1;
  const int row = base + m;
  const bool live = row < N;

  float vr[8] = {0.f, 0.f, 0.f, 0.f, 0.f, 0.f, 0.f, 0.f};
  if (q < 2) {
    *(float4*)(vr + 0) = *(const float4*)(vcp + (size_t)node * 16 + q * 8);
    *(float4*)(vr + 4) = *(const float4*)(vcp + (size_t)node * 16 + q * 8 + 4);
  }
  U8h V0;
  conv8_rne(vr, V0);
  float xr[16];
  load_row(x + (size_t)node * 64 + q * 8, xr);
  U8h X0, X1;
  conv8_rne(xr + 0, X0);
  conv8_rne(xr + 8, X1);

  float* hb = hbuf[wv];
#pragma unroll
  for (int p = 0; p < 4; ++p) {
    const int slot = p * 64;
    f32x4 o[4];
#pragma unroll
    for (int t = 0; t < 4; ++t) o[t] = (f32x4){0.f, 0.f, 0.f, 0.f};
    if (p == 0 || p == 2) {  // hyB (src) / hyA (dst), single K=32 chunk with zero-padded A
      const _Float16* W = (p == 0) ? hyB1s : hyB1;
#pragma unroll
      for (int t = 0; t < 4; ++t) {
        f16x8 b = *(const f16x8*)(W + ((size_t)t * 64 + lane) * 8);
        o[t] = __builtin_amdgcn_mfma_f32_16x16x32_f16(V0.v, b, o[t], 0, 0, 0);
      }
    } else {                 // C_fx (fx chunks 0,1) / D_fx (fx chunks 2,3)
      const int c0 = (p == 1) ? 0 : 2;
#pragma unroll
      for (int t = 0; t < 4; ++t) {
        f16x8 b0 = *(const f16x8*)(fxB1 + ((size_t)((c0 + 0) * 4 + t) * 64 + lane) * 8);
        f16x8 b1 = *(const f16x8*)(fxB1 + ((size_t)((c0 + 1) * 4 + t) * 64 + lane) * 8);
        o[t] = __builtin_amdgcn_mfma_f32_16x16x32_f16(X0.v, b0, o[t], 0, 0, 0);
        o[t] = __builtin_amdgcn_mfma_f32_16x16x32_f16(X1.v, b1, o[t], 0, 0, 0);
      }
    }
#pragma unroll
    for (int t = 0; t < 4; ++t)
#pragma unroll
      for (int r = 0; r < 4; ++r)
        hb[(q * 4 + r) * 68 + t * 16 + m] = o[t][r];
    float pv[16];
    load_row(hb + m * 68 + q * 8, pv);
    U8h P0, P1;
    conv8_rne(pv + 0, P0);
    conv8_rne(pv + 8, P1);
    if (live) {
      _Float16* pp = P + (size_t)row * 256 + slot;
      *(f16x8*)(pp + q * 8)      = P0.v;
      *(f16x8*)(pp + 32 + q * 8) = P1.v;
    }
  }
}

// ---------------- unified edge kernel: (hy|fy) L2 + y update + fx via projections ----------
__global__ __launch_bounds__(256) void k_edge(
    const _Float16* __restrict__ P, _Float16* __restrict__ y,
    const int* __restrict__ src, const int* __restrict__ dst,
    const float* __restrict__ yb1,
    const _Float16* __restrict__ yB2, const float* __restrict__ yb2,
    const _Float16* __restrict__ xB1, const float* __restrict__ xb1,
    const _Float16* __restrict__ xB2, const float* __restrict__ xb2,
    float* __restrict__ xnew, int E, int useOldY, int storeY) {
  __shared__ float hbuf[4][16 * 68];
  const int lane = threadIdx.x & 63;
  const int wv = threadIdx.x >> 6;
  const int m = lane & 15, q = lane >> 4;
  const int base = blockIdx.x * 64 + wv * 16;
  int em = base + m; if (em >= E) em = E - 1;
  const int s = src[em], d = dst[em];
  const int row = base + m;
  const bool live = row < E;

  // gathers: src fields [B_fy|C_fx], dst fields [A_fy|D_fx], optionally old y
  const _Float16* Ps = P + (size_t)s * 256;
  const _Float16* Pd = P + (size_t)d * 256 + 128;
  U8h Bf0, Bf1, Cf0, Cf1, Af0, Af1, Df0, Df1;
  Bf0.v = *(const f16x8*)(Ps + q * 8);       Bf1.v = *(const f16x8*)(Ps + 32 + q * 8);
  Cf0.v = *(const f16x8*)(Ps + 64 + q * 8);  Cf1.v = *(const f16x8*)(Ps + 96 + q * 8);
  Af0.v = *(const f16x8*)(Pd + q * 8);       Af1.v = *(const f16x8*)(Pd + 32 + q * 8);
  Df0.v = *(const f16x8*)(Pd + 64 + q * 8);  Df1.v = *(const f16x8*)(Pd + 96 + q * 8);
  U8h Ho0, Ho1;
  if (useOldY) {
    size_t yo = (size_t)em * 64 + q * 8;
    Ho0.v = *(const f16x8*)(y + yo);
    Ho1.v = *(const f16x8*)(y + yo + 32);
  }

  // h_fy = relu(A(d) + B(s) + yb1)  (row layout, no MFMA)
  float bias1[16];
  *(float4*)(bias1 + 0)  = *(const float4*)(yb1 + q * 8);
  *(float4*)(bias1 + 4)  = *(const float4*)(yb1 + q * 8 + 4);
  *(float4*)(bias1 + 8)  = *(const float4*)(yb1 + 32 + q * 8);
  *(float4*)(bias1 + 12) = *(const float4*)(yb1 + 32 + q * 8 + 4);
  float hrow[16];
#pragma unroll
  for (int i = 0; i < 8; ++i) {
    hrow[i]     = fmaxf((float)Af0.s[i] + (float)Bf0.s[i] + bias1[i], 0.f);
    hrow[8 + i] = fmaxf((float)Af1.s[i] + (float)Bf1.s[i] + bias1[8 + i], 0.f);
  }
  U8h H0, H1;
  conv8_rne(hrow + 0, H0);
  conv8_rne(hrow + 8, H1);

  // fy L2 (8 MFMA, C-layout)
  f32x4 o[4];
#pragma unroll
  for (int t = 0; t < 4; ++t) { float bv = yb2[t * 16 + m]; o[t] = (f32x4){bv, bv, bv, bv}; }
#pragma unroll
  for (int t = 0; t < 4; ++t) {
    f16x8 b0 = *(const f16x8*)(yB2 + ((size_t)(0 * 4 + t) * 64 + lane) * 8);
    f16x8 b1 = *(const f16x8*)(yB2 + ((size_t)(1 * 4 + t) * 64 + lane) * 8);
    o[t] = __builtin_amdgcn_mfma_f32_16x16x32_f16(H0.v, b0, o[t], 0, 0, 0);
    o[t] = __builtin_amdgcn_mfma_f32_16x16x32_f16(H1.v, b1, o[t], 0, 0, 0);
  }

  // LDS trip 1: C -> row; y_new = max(y_old, out); store
  float* hb = hbuf[wv];
#pragma unroll
  for (int t = 0; t < 4; ++t)
#pragma unroll
    for (int r = 0; r < 4; ++r)
      hb[(q * 4 + r) * 68 + t * 16 + m] = o[t][r];
  float nv[16];
  load_row(hb + m * 68 + q * 8, nv);
  if (useOldY) {
#pragma unroll
    for (int i = 0; i < 8; ++i) {
      nv[i]     = fmaxf(nv[i], (float)Ho0.s[i]);
      nv[8 + i] = fmaxf(nv[8 + i], (float)Ho1.s[i]);
    }
  }
  U8h Yh0, Yh1;
  conv8_rne(nv + 0, Yh0);
  conv8_rne(nv + 8, Yh1);
  if (live && storeY) {
    size_t yo = (size_t)row * 64 + q * 8;
    *(f16x8*)(y + yo)      = Yh0.v;
    *(f16x8*)(y + yo + 32) = Yh1.v;
  }

  // Py = y·W3 + fx_b1 (8 MFMA, C-layout) -> LDS trip 2 -> row
  f32x4 a2[4];
#pragma unroll
  for (int t = 0; t < 4; ++t) { float bv = xb1[t * 16 + m]; a2[t] = (f32x4){bv, bv, bv, bv}; }
#pragma unroll
  for (int t = 0; t < 4; ++t) {
    f16x8 b4 = *(const f16x8*)(xB1 + ((size_t)(4 * 4 + t) * 64 + lane) * 8);
    f16x8 b5 = *(const f16x8*)(xB1 + ((size_t)(5 * 4 + t) * 64 + lane) * 8);
    a2[t] = __builtin_amdgcn_mfma_f32_16x16x32_f16(Yh0.v, b4, a2[t], 0, 0, 0);
    a2[t] = __builtin_amdgcn_mfma_f32_16x16x32_f16(Yh1.v, b5, a2[t], 0, 0, 0);
  }
#pragma unroll
  for (int t = 0; t < 4; ++t)
#pragma unroll
    for (int r = 0; r < 4; ++r)
      hb[(q * 4 + r) * 68 + t * 16 + m] = a2[t][r];
  float pyv[16];
  load_row(hb + m * 68 + q * 8, pyv);

  // h_fx = relu(C(s) + D(d) + Py)
  float g[16];
#pragma unroll
  for (int i = 0; i < 8; ++i) {
    g[i]     = fmaxf((float)Cf0.s[i] + (float)Df0.s[i] + pyv[i], 0.f);
    g[8 + i] = fmaxf((float)Cf1.s[i] + (float)Df1.s[i] + pyv[8 + i], 0.f);
  }
  U8h G0, G1;
  conv8_rne(g + 0, G0);
  conv8_rne(g + 8, G1);

  // fx L2 (8 MFMA, C-layout) -> emit
  f32x4 o2[4];
#pragma unroll
  for (int t = 0; t < 4; ++t) { float bv = xb2[t * 16 + m]; o2[t] = (f32x4){bv, bv, bv, bv}; }
#pragma unroll
  for (int t = 0; t < 4; ++t) {
    f16x8 b0 = *(const f16x8*)(xB2 + ((size_t)(0 * 4 + t) * 64 + lane) * 8);
    f16x8 b1 = *(const f16x8*)(xB2 + ((size_t)(1 * 4 + t) * 64 + lane) * 8);
    o2[t] = __builtin_amdgcn_mfma_f32_16x16x32_f16(G0.v, b0, o2[t], 0, 0, 0);
    o2[t] = __builtin_amdgcn_mfma_f32_16x16x32_f16(G1.v, b1, o2[t], 0, 0, 0);
  }

  int dd[4];
  int e0 = base + q * 4;
#pragma unroll
  for (int r = 0; r < 4; ++r) {
    int e2 = e0 + r;
    dd[r] = (e2 < E) ? dst[e2] : -1;
  }
  RunCtx rc = run_ctx(dd, lane, q);
#pragma unroll
  for (int t = 0; t < 4; ++t) emit_t(o2[t], dd, rc, lane, m, t, xnew);
}

// ---------------- feta (MFMA): out = w3 . relu(MLP2(x)) ----------------
__global__ __launch_bounds__(256) void k_feta2(
    const float* __restrict__ x,
    const _Float16* __restrict__ B1, const float* __restrict__ b1,
    const _Float16* __restrict__ B2, const float* __restrict__ b2,
    const float* __restrict__ w3, float* __restrict__ out, int N) {
  __shared__ float hbuf[4][16 * 68];
  const int lane = threadIdx.x & 63;
  const int wv = threadIdx.x >> 6;
  const int m = lane & 15, q = lane >> 4;
  const int base = blockIdx.x * 64 + wv * 16;
  int node = base + m; if (node >= N) node = N - 1;
  float fs[16];
  load_row(x + (size_t)node * 64 + q * 8, fs);
  U8h Ah[2], Al[2];
  dec8h(fs + 0, Ah[0], Al[0]);
  dec8h(fs + 8, Ah[1], Al[1]);

  f32x4 acc[4];
#pragma unroll
  for (int t = 0; t < 4; ++t) { float bv = b1[t * 16 + m]; acc[t] = (f32x4){bv, bv, bv, bv}; }
#pragma unroll
  for (int c = 0; c < 2; ++c) {
#pragma unroll
    for (int t = 0; t < 4; ++t) {
      f16x8 b = *(const f16x8*)(B1 + ((size_t)(c * 4 + t) * 64 + lane) * 8);
      acc[t] = __builtin_amdgcn_mfma_f32_16x16x32_f16(Ah[c].v, b, acc[t], 0, 0, 0);
      acc[t] = __builtin_amdgcn_mfma_f32_16x16x32_f16(Al[c].v, b, acc[t], 0, 0, 0);
    }
  }

  float* hb = hbuf[wv];
#pragma unroll
  for (int t = 0; t < 4; ++t)
#pragma unroll
    for (int r = 0; r < 4; ++r)
      hb[(q * 4 + r) * 68 + t * 16 + m] = fmaxf(acc[t][r], 0.f);

  float fh[16];
  load_row(hb + m * 68 + q * 8, fh);
  U8h A2h[2], A2l[2];
  dec8h(fh + 0, A2h[0], A2l[0]);
  dec8h(fh + 8, A2h[1], A2l[1]);

  f32x4 acc2[4];
#pragma unroll
  for (int t = 0; t < 4; ++t) { float bv = b2[t * 16 + m]; acc2[t] = (f32x4){bv, bv, bv, bv}; }
#pragma unroll
  for (int c = 0; c < 2; ++c) {
#pragma unroll
    for (int t = 0; t < 4; ++t) {
      f16x8 b = *(const f16x8*)(B2 + ((size_t)(c * 4 + t) * 64 + lane) * 8);
      acc2[t] = __builtin_amdgcn_mfma_f32_16x16x32_f16(A2h[c].v, b, acc2[t], 0, 0, 0);
      acc2[t] = __builtin_amdgcn_mfma_f32_16x16x32_f16(A2l[c].v, b, acc2[t], 0, 0, 0);
    }
  }

  float w3v[4];
#pragma unroll
  for (int t = 0; t < 4; ++t) w3v[t] = w3[t * 16 + m];
#pragma unroll
  for (int r = 0; r < 4; ++r) {
    float s = 0.f;
#pragma unroll
    for (int t = 0; t < 4; ++t) s += fmaxf(acc2[t][r], 0.f) * w3v[t];
    s += __shfl_xor(s, 1, 64);
    s += __shfl_xor(s, 2, 64);
    s += __shfl_xor(s, 4, 64);
    s += __shfl_xor(s, 8, 64);
    int row = base + q * 4 + r;
    if (m == 0 && row < N) out[row] = s;
  }
}

extern "C" void kernel_launch(void* const* d_in, const int* in_sizes, int n_in,
                              void* d_out, int out_size, void* d_ws, size_t ws_size,
                              hipStream_t stream) {
  const float* v      = (const float*)d_in[0];
  const float* labels = (const float*)d_in[1];
  const int*   ei     = (const int*)d_in[2];
  const float* hx_w1 = (const float*)d_in[4];
  const float* hx_b1 = (const float*)d_in[5];
  const float* hx_w2 = (const float*)d_in[6];
  const float* hx_b2 = (const float*)d_in[7];
  const float* hy_w1 = (const float*)d_in[8];
  const float* hy_b1 = (const float*)d_in[9];
  const float* hy_w2 = (const float*)d_in[10];
  const float* hy_b2 = (const float*)d_in[11];
  const float* fx_w1 = (const float*)d_in[12];
  const float* fx_b1 = (const float*)d_in[13];
  const float* fx_w2 = (const float*)d_in[14];
  const float* fx_b2 = (const float*)d_in[15];
  const float* fy_w1 = (const float*)d_in[16];
  const float* fy_b1 = (const float*)d_in[17];
  const float* fy_w2 = (const float*)d_in[18];
  const float* fy_b2 = (const float*)d_in[19];
  const float* feta_w1 = (const float*)d_in[20];
  const float* feta_b1 = (const float*)d_in[21];
  const float* feta_w2 = (const float*)d_in[22];
  const float* feta_b2 = (const float*)d_in[23];
  const float* feta_w3 = (const float*)d_in[24];

  int N = in_sizes[0] / 7;
  int E = in_sizes[2] / 2;
  const int* src = ei;
  const int* dst = ei + E;

  char* wsb = (char*)d_ws;
  float* goal = (float*)wsb;                                     // 16 f
  u64* goalkey = (u64*)(wsb + 64);
  float* b1p = (float*)(wsb + 96);                               // 64 f
  float* xa = (float*)(wsb + 512);                               // N*64 f
  float* xb = xa + (size_t)N * 64;                               // N*64 f
  _Float16* y = (_Float16*)(xb + (size_t)N * 64);                // E*64 f16
  _Float16* P = y + (size_t)E * 64;                              // N*256 f16
  _Float16* wp = P + (size_t)N * 256;                            // 51200 f16
  float* vcp = (float*)(wp + 51200);                             // N*16 f
  int* deg = (int*)(vcp + (size_t)N * 16);                       // N
  int* cursor = deg + N;                                         // N
  int* srcp = cursor + N;                                        // E
  int* dstp = srcp + E;                                          // E
  int* bsum = dstp + E;                                          // 64

  _Float16* fxB1  = wp;          _Float16* fxB2 = wp + 12288;
  _Float16* fyB1  = wp + 16384;  _Float16* fyB2 = wp + 24576;
  _Float16* hyB1  = wp + 28672;  _Float16* hyB2 = wp + 30720;
  _Float16* hxB1  = wp + 34816;  _Float16* hxB2 = wp + 36864;
  _Float16* feB1  = wp + 40960;  _Float16* feB2 = wp + 45056;
  _Float16* hyB1s = wp + 49152;

  int SB = (N + 1023) / 1024;

  hipMemsetAsync(deg, 0, (size_t)N * 4, stream);
  k_prep<<<25, 256, 0, stream>>>(fx_w1, fx_w2, fy_w1, fy_w2, hy_w1, hy_w2,
                                 hx_w1, hx_w2, feta_w1, feta_w2, wp, goalkey);
  k_vch<<<(N * 16 + 255) / 256, 256, 0, stream>>>(v, labels, vcp, N, dst, E, deg, goalkey);
  k_goal2b<<<1, 64, 0, stream>>>(v, labels, goalkey, hx_w1, hx_b1, goal, b1p);
  k_scan1<<<SB, 256, 0, stream>>>(deg, N, bsum);
  k_scan3<<<SB, 256, 0, stream>>>(deg, bsum, N, cursor);
  k_scatter<<<(E + 255) / 256, 256, 0, stream>>>(src, dst, E, cursor, srcp, dstp);

  int NB = (N + 63) / 64;
  int EB = (E + 63) / 64;

  // x1 -> xa (working) + xb (t=0 atomic seed)
  k_hx2<<<NB, 256, 0, stream>>>(vcp, goal, hxB1, b1p, hxB2, hx_b2, xa, xb, N);
  // projections for t=0: hy (from vcp) + fx (from x1)
  k_proj0<<<NB, 256, 0, stream>>>(vcp, xa, hyB1, hyB1s, fxB1, P, N);
  // t=0: y0 = hy; x2 = max(x1, agg fx) -> xb
  k_edge<<<EB, 256, 0, stream>>>(P, y, srcp, dstp, hy_b1, hyB2, hy_b2,
                                 fxB1, fx_b1, fxB2, fx_b2, xb, E, 0, 1);
  // projections from x2 + seed copy xb->xa
  k_proj<<<NB, 256, 0, stream>>>(xb, fyB1, fxB1, P, xa, N);
  // t=1
  k_edge<<<EB, 256, 0, stream>>>(P, y, srcp, dstp, fy_b1, fyB2, fy_b2,
                                 fxB1, fx_b1, fxB2, fx_b2, xa, E, 1, 1);
  // projections from x3 + seed copy xa->xb
  k_proj<<<NB, 256, 0, stream>>>(xa, fyB1, fxB1, P, xb, N);
  // t=2 (y dead after: skip its store)
  k_edge<<<EB, 256, 0, stream>>>(P, y, srcp, dstp, fy_b1, fyB2, fy_b2,
                                 fxB1, fx_b1, fxB2, fx_b2, xb, E, 1, 0);

  k_feta2<<<NB, 256, 0, stream>>>(xb, feB1, feta_b1, feB2, feta_b2, feta_w3,
                                  (float*)d_out, N);
}

// Round 13
// 342.268 us; speedup vs baseline: 1.0632x; 1.0632x over previous
//
#include <hip/hip_runtime.h>
#include <math.h>

typedef unsigned short u16;
typedef unsigned int u32;
typedef unsigned long long u64;
typedef __attribute__((ext_vector_type(8))) _Float16 f16x8;
typedef __attribute__((ext_vector_type(2))) _Float16 f16x2;
typedef __attribute__((ext_vector_type(4))) float f32x4;

union U8h { f16x8 v; f16x2 p[4]; u32 u[4]; _Float16 s[8]; };
union U4h { _Float16 s[4]; u64 u; };

__device__ __forceinline__ void atomicMaxF(float* addr, float val) {
  if (val >= 0.0f) {
    atomicMax((int*)addr, __float_as_int(val));
  } else {
    atomicMin((unsigned int*)addr, (unsigned int)__float_as_int(val));
  }
}

__device__ __forceinline__ f16x2 pk(float a, float b) {
  return __builtin_bit_cast(f16x2, __builtin_amdgcn_cvt_pkrtz(a, b));
}

// split 8 fp32 -> fp16 hi (RTZ) + lo (residual): hi+lo exact to ~2^-22
__device__ __forceinline__ void dec8h(const float* f, U8h& h, U8h& l) {
#pragma unroll
  for (int i = 0; i < 4; ++i) {
    float a = f[2 * i], b = f[2 * i + 1];
    f16x2 hp = pk(a, b);
    float ra = a - (float)hp[0];
    float rb = b - (float)hp[1];
    h.p[i] = hp;
    l.p[i] = pk(ra, rb);
  }
}

__device__ __forceinline__ void conv8_rne(const float* f, U8h& h) {
#pragma unroll
  for (int i = 0; i < 8; ++i) h.s[i] = (_Float16)f[i];
}

// lane's two 8-float chunks of a 64-float row (cols q*8.. and 32+q*8..)
__device__ __forceinline__ void load_row(const float* p, float* f) {
  *(float4*)(f + 0)  = *(const float4*)(p);
  *(float4*)(f + 4)  = *(const float4*)(p + 4);
  *(float4*)(f + 8)  = *(const float4*)(p + 32);
  *(float4*)(f + 12) = *(const float4*)(p + 36);
}

// ---- cross-q segmented-run merge for dst-sorted scatter-max ----
struct RunCtx { bool chain1, chain2, chain3, suppress; };

__device__ __forceinline__ RunCtx run_ctx(const int dd[4], int lane, int q) {
  bool allsame = (dd[0] == dd[1]) && (dd[1] == dd[2]) && (dd[2] == dd[3]);
  int nfd1 = __shfl(dd[0], lane + 16, 64);
  int nfd2 = __shfl(dd[0], lane + 32, 64);
  int nfd3 = __shfl(dd[0], lane + 48, 64);
  int as = allsame ? 1 : 0;
  int nas1 = __shfl(as, lane + 16, 64);
  int nas2 = __shfl(as, lane + 32, 64);
  int pld = __shfl(dd[3], lane - 16, 64);
  RunCtx c;
  c.chain1 = (q < 3) && (nfd1 == dd[3]);
  c.chain2 = c.chain1 && (nas1 != 0) && (q < 2) && (nfd2 == dd[3]);
  c.chain3 = c.chain2 && (nas2 != 0) && (q < 1) && (nfd3 == dd[3]);
  c.suppress = (q > 0) && (pld == dd[0]);
  return c;
}

__device__ __forceinline__ void emit_t(const f32x4 o, const int dd[4], const RunCtx c,
                                       int lane, int m, int t, float* __restrict__ xnew) {
  float fv = o[0];
  bool c01 = dd[1] == dd[0];
  fv = c01 ? fmaxf(fv, o[1]) : fv;
  bool c012 = c01 && (dd[2] == dd[1]);
  fv = c012 ? fmaxf(fv, o[2]) : fv;
  bool c0123 = c012 && (dd[3] == dd[2]);
  fv = c0123 ? fmaxf(fv, o[3]) : fv;
  float nfv1 = __shfl(fv, lane + 16, 64);
  float nfv2 = __shfl(fv, lane + 32, 64);
  float nfv3 = __shfl(fv, lane + 48, 64);
  float run = o[0];
  bool first = true;
#pragma unroll
  for (int r = 0; r < 4; ++r) {
    if (r > 0) run = (dd[r] == dd[r - 1]) ? fmaxf(run, o[r]) : o[r];
    bool end = (r == 3) || (dd[r + 1] != dd[r]);
    if (end) {
      float val = run;
      if (r == 3) {
        if (c.chain1) val = fmaxf(val, nfv1);
        if (c.chain2) val = fmaxf(val, nfv2);
        if (c.chain3) val = fmaxf(val, nfv3);
      }
      if (!(first && c.suppress) && dd[r] >= 0)
        atomicMaxF(&xnew[(size_t)dd[r] * 64 + t * 16 + m], val);
      first = false;
    }
  }
}

// ---------------- vcp build + degree histogram + goal argmax (fused) ----------------
__global__ __launch_bounds__(256) void k_vch(const float* __restrict__ v,
                                             const float* __restrict__ labels,
                                             float* __restrict__ vcp, int N,
                                             const int* __restrict__ dst, int E,
                                             int* __restrict__ deg, u64* __restrict__ key) {
  int tid = blockIdx.x * 256 + threadIdx.x;
  if (tid < N * 16) {
    int n = tid >> 4, c = tid & 15;
    float val = 0.f;
    if (c < 7) val = v[(size_t)n * 7 + c];
    else if (c == 7) val = labels[2 * (size_t)n];
    else if (c == 8) val = labels[2 * (size_t)n + 1];
    vcp[tid] = val;
  }
  if (tid < E) atomicAdd(&deg[dst[tid]], 1);
  if ((tid & ~63) < N) {
    float val = (tid < N) ? labels[2 * (size_t)tid + 1] : 0.0f;
    u64 k = ((u64)__float_as_uint(fmaxf(val, 0.0f)) << 32) | (u32)(~(u32)tid);
#pragma unroll
    for (int off = 32; off > 0; off >>= 1) {
      u64 o = __shfl_xor(k, off, 64);
      if (o > k) k = o;
    }
    if ((threadIdx.x & 63) == 0) atomicMax(key, k);
  }
}

// ---------------- goal extract + hx goal-folded bias ----------------
__global__ void k_goal2b(const float* __restrict__ v, const float* __restrict__ labels,
                         const u64* __restrict__ key,
                         const float* __restrict__ hxw1, const float* __restrict__ hxb1,
                         float* __restrict__ goal, float* __restrict__ b1p) {
  __shared__ float g[9];
  int gi = (int)(~(u32)(*key));
  int c = threadIdx.x;
  if (c < 9) {
    float gv = (c < 7) ? v[7 * (size_t)gi + c] : labels[2 * (size_t)gi + (c - 7)];
    g[c] = gv;
    goal[c] = gv;
  }
  __syncthreads();
  if (c < 64) {
    float s = hxb1[c];
#pragma unroll
    for (int k = 0; k < 9; ++k) s += g[k] * hxw1[(9 + k) * 64 + c];
    b1p[c] = s;
  }
}

// ---------------- weight prep: frag-major fp16 for all MFMA MLPs ----------------
__global__ __launch_bounds__(256) void k_prep(const float* __restrict__ fxw1, const float* __restrict__ fxw2,
                                              const float* __restrict__ fyw1, const float* __restrict__ fyw2,
                                              const float* __restrict__ hyw1, const float* __restrict__ hyw2,
                                              const float* __restrict__ hxw1, const float* __restrict__ hxw2,
                                              const float* __restrict__ few1, const float* __restrict__ few2,
                                              _Float16* __restrict__ wp, u64* __restrict__ goalkey) {
  if (blockIdx.x == 0 && threadIdx.x == 0) *goalkey = 0;  // runs before k_vch's atomics
  _Float16* fxB1 = wp;           // 12288
  _Float16* fxB2 = wp + 12288;   // 4096
  _Float16* fyB1 = wp + 16384;   // 8192
  _Float16* fyB2 = wp + 24576;   // 4096
  _Float16* hyB1 = wp + 28672;   // 2048
  _Float16* hyB2 = wp + 30720;   // 4096
  _Float16* hxB1 = wp + 34816;   // 2048
  _Float16* hxB2 = wp + 36864;   // 4096
  _Float16* feB1 = wp + 40960;   // 4096
  _Float16* feB2 = wp + 45056;   // 4096
  int tid = blockIdx.x * 256 + threadIdx.x;
  int which, id;
  _Float16* oh;
  if (tid < 1536)      { which = 0; id = tid;        oh = fxB1; }
  else if (tid < 2048) { which = 1; id = tid - 1536; oh = fxB2; }
  else if (tid < 3072) { which = 2; id = tid - 2048; oh = fyB1; }
  else if (tid < 3584) { which = 3; id = tid - 3072; oh = fyB2; }
  else if (tid < 3840) { which = 4; id = tid - 3584; oh = hyB1; }
  else if (tid < 4352) { which = 5; id = tid - 3840; oh = hyB2; }
  else if (tid < 4608) { which = 6; id = tid - 4352; oh = hxB1; }
  else if (tid < 5120) { which = 7; id = tid - 4608; oh = hxB2; }
  else if (tid < 5632) { which = 8; id = tid - 5120; oh = feB1; }
  else if (tid < 6144) { which = 9; id = tid - 5632; oh = feB2; }
  else return;
  int lane = id & 63;
  int q = lane >> 4, col = lane & 15;
  int c = id >> 8, t = (id >> 6) & 3;
#pragma unroll
  for (int j = 0; j < 8; ++j) {
    int k = c * 32 + q * 8 + j;
    int n = t * 16 + col;
    float w;
    if (which == 0) {
      w = (k < 64)  ? fxw1[k * 64 + n] + fxw1[(k + 64) * 64 + n]
        : (k < 128) ? fxw1[(k + 64) * 64 + n] - fxw1[(k - 64) * 64 + n]
                    : fxw1[(k + 64) * 64 + n];
    } else if (which == 1) {
      w = fxw2[k * 64 + n];
    } else if (which == 2) {
      w = (k < 64) ? fyw1[k * 64 + n] + fyw1[(k + 64) * 64 + n]
                   : fyw1[(k + 64) * 64 + n] - fyw1[(k - 64) * 64 + n];
    } else if (which == 3) {
      w = fyw2[k * 64 + n];
    } else if (which == 4) {
      if (k <= 8)                  w = hyw1[k * 64 + n] + hyw1[(k + 9) * 64 + n];
      else if (k >= 16 && k <= 24) w = hyw1[(k + 2) * 64 + n] - hyw1[(k - 16) * 64 + n];
      else                         w = 0.f;
    } else if (which == 5) {
      w = hyw2[k * 64 + n];
    } else if (which == 6) {
      w = (k < 9) ? hxw1[k * 64 + n] : (k < 27) ? hxw1[(k + 9) * 64 + n] : 0.f;
    } else if (which == 7) {
      w = hxw2[k * 64 + n];
    } else if (which == 8) {
      w = few1[k * 64 + n];
    } else {
      w = few2[k * 64 + n];
    }
    oh[id * 8 + j] = (_Float16)w;
  }
}

// ---------------- CSR scan ----------------
__global__ __launch_bounds__(256) void k_scan1(const int* __restrict__ deg, int N,
                                               int* __restrict__ bsum) {
  __shared__ int red[256];
  int b = blockIdx.x;
  int s = 0;
  for (int i = threadIdx.x; i < 1024; i += 256) {
    int idx = b * 1024 + i;
    s += (idx < N) ? deg[idx] : 0;
  }
  red[threadIdx.x] = s; __syncthreads();
  for (int st = 128; st > 0; st >>= 1) {
    if (threadIdx.x < st) red[threadIdx.x] += red[threadIdx.x + st];
    __syncthreads();
  }
  if (threadIdx.x == 0) bsum[b] = red[0];
}

__global__ __launch_bounds__(256) void k_scan3(const int* __restrict__ deg,
                                               const int* __restrict__ bsum, int N,
                                               int* __restrict__ cursor) {
  __shared__ int lsum[256];
  __shared__ int bofs;
  int b = blockIdx.x;
  int tid = threadIdx.x;
  if (tid == 0) {
    int a = 0;
    for (int i = 0; i < b; ++i) a += bsum[i];
    bofs = a;
  }
  int base_i = b * 1024 + tid * 4;
  int loc[4]; int s = 0;
#pragma unroll
  for (int j = 0; j < 4; ++j) {
    int v = (base_i + j < N) ? deg[base_i + j] : 0;
    loc[j] = s; s += v;
  }
  lsum[tid] = s; __syncthreads();
  for (int st = 1; st < 256; st <<= 1) {
    int add = (tid >= st) ? lsum[tid - st] : 0;
    __syncthreads();
    lsum[tid] += add;
    __syncthreads();
  }
  int toff = bofs + lsum[tid] - s;
#pragma unroll
  for (int j = 0; j < 4; ++j) {
    if (base_i + j < N) cursor[base_i + j] = toff + loc[j];
  }
}

__global__ __launch_bounds__(256) void k_scatter(const int* __restrict__ src,
                                                 const int* __restrict__ dst, int E,
                                                 int* __restrict__ cursor,
                                                 int* __restrict__ srcp, int* __restrict__ dstp) {
  int e = blockIdx.x * 256 + threadIdx.x;
  if (e < E) {
    int d = dst[e];
    int pos = atomicAdd(&cursor[d], 1);
    srcp[pos] = src[e];
    dstp[pos] = d;
  }
}

// ---------------- hx (MFMA): x0 = MLP2([vc; d; d^2] K=32, goal-folded bias) ----------
// writes fp32 x to two buffers + fp16 shadow for edge-kernel gathers
__global__ __launch_bounds__(256) void k_hx2(
    const float* __restrict__ vcp, const float* __restrict__ goal,
    const _Float16* __restrict__ B1, const float* __restrict__ b1p,
    const _Float16* __restrict__ B2, const float* __restrict__ b2,
    float* __restrict__ xout, float* __restrict__ xout2, _Float16* __restrict__ xh, int N) {
  __shared__ float hbuf[4][16 * 68];
  const int lane = threadIdx.x & 63;
  const int wv = threadIdx.x >> 6;
  const int m = lane & 15, q = lane >> 4;
  const int base = blockIdx.x * 64 + wv * 16;
  int node = base + m; if (node >= N) node = N - 1;
  float vc[12];
  *(float4*)(vc + 0) = *(const float4*)(vcp + (size_t)node * 16);
  *(float4*)(vc + 4) = *(const float4*)(vcp + (size_t)node * 16 + 4);
  *(float4*)(vc + 8) = *(const float4*)(vcp + (size_t)node * 16 + 8);
  float gl[9];
#pragma unroll
  for (int i = 0; i < 9; ++i) gl[i] = goal[i];
  float f[8];
#pragma unroll
  for (int j = 0; j < 8; ++j) {
    int idx = q * 8 + j;
    float val = 0.f;
    if (idx < 9) val = vc[idx];
    else if (idx < 18) val = vc[idx - 9] - gl[idx - 9];
    else if (idx < 27) { float dv = vc[idx - 18] - gl[idx - 18]; val = dv * dv; }
    f[j] = val;
  }
  U8h Ah, Al;
  dec8h(f, Ah, Al);

  f32x4 acc[4];
#pragma unroll
  for (int t = 0; t < 4; ++t) { float bv = b1p[t * 16 + m]; acc[t] = (f32x4){bv, bv, bv, bv}; }
#pragma unroll
  for (int t = 0; t < 4; ++t) {
    f16x8 b = *(const f16x8*)(B1 + ((size_t)t * 64 + lane) * 8);
    acc[t] = __builtin_amdgcn_mfma_f32_16x16x32_f16(Ah.v, b, acc[t], 0, 0, 0);
    acc[t] = __builtin_amdgcn_mfma_f32_16x16x32_f16(Al.v, b, acc[t], 0, 0, 0);
  }

  float* hb = hbuf[wv];
#pragma unroll
  for (int t = 0; t < 4; ++t)
#pragma unroll
    for (int r = 0; r < 4; ++r)
      hb[(q * 4 + r) * 68 + t * 16 + m] = fmaxf(acc[t][r], 0.f);

  float fh[16];
  load_row(hb + m * 68 + q * 8, fh);
  U8h A2h[2], A2l[2];
  dec8h(fh + 0, A2h[0], A2l[0]);
  dec8h(fh + 8, A2h[1], A2l[1]);

  f32x4 acc2[4];
#pragma unroll
  for (int t = 0; t < 4; ++t) { float bv = b2[t * 16 + m]; acc2[t] = (f32x4){bv, bv, bv, bv}; }
#pragma unroll
  for (int c = 0; c < 2; ++c) {
#pragma unroll
    for (int t = 0; t < 4; ++t) {
      f16x8 b = *(const f16x8*)(B2 + ((size_t)(c * 4 + t) * 64 + lane) * 8);
      acc2[t] = __builtin_amdgcn_mfma_f32_16x16x32_f16(A2h[c].v, b, acc2[t], 0, 0, 0);
      acc2[t] = __builtin_amdgcn_mfma_f32_16x16x32_f16(A2l[c].v, b, acc2[t], 0, 0, 0);
    }
  }

#pragma unroll
  for (int t = 0; t < 4; ++t)
#pragma unroll
    for (int r = 0; r < 4; ++r)
      hb[(q * 4 + r) * 68 + t * 16 + m] = acc2[t][r];

  int row = base + m;
  if (row < N) {
    float ov[16];
    const float* orow = hb + m * 68 + q * 16;
    *(float4*)(ov + 0)  = *(const float4*)(orow);
    *(float4*)(ov + 4)  = *(const float4*)(orow + 4);
    *(float4*)(ov + 8)  = *(const float4*)(orow + 8);
    *(float4*)(ov + 12) = *(const float4*)(orow + 12);
    float* p1 = xout + (size_t)row * 64 + q * 16;
    float* p2 = xout2 + (size_t)row * 64 + q * 16;
#pragma unroll
    for (int i = 0; i < 4; ++i) {
      *(float4*)(p1 + i * 4) = *(const float4*)(ov + i * 4);
      *(float4*)(p2 + i * 4) = *(const float4*)(ov + i * 4);
    }
    U8h X0, X1;
    conv8_rne(ov + 0, X0);
    conv8_rne(ov + 8, X1);
    *(f16x8*)(xh + (size_t)row * 64 + q * 16)     = X0.v;
    *(f16x8*)(xh + (size_t)row * 64 + q * 16 + 8) = X1.v;
  }
}

// ---------------- convert-copy: fp32 seed copy + fp16 gather shadow ----------------
__global__ __launch_bounds__(256) void k_cc(const float4* __restrict__ s,
                                            float4* __restrict__ d,
                                            _Float16* __restrict__ h16, int n4) {
  int i = blockIdx.x * 256 + threadIdx.x;
  if (i < n4) {
    float4 v = s[i];
    d[i] = v;
    U4h o;
    o.s[0] = (_Float16)v.x; o.s[1] = (_Float16)v.y;
    o.s[2] = (_Float16)v.z; o.s[3] = (_Float16)v.w;
    *(u64*)(h16 + (size_t)i * 4) = o.u;
  }
}

// ---------------- fused hy + fx (t=0): x gathered fp16 ----------------
__global__ __launch_bounds__(256) void k_hyfx(
    const float* __restrict__ vcp, const _Float16* __restrict__ xh,
    const int* __restrict__ src, const int* __restrict__ dst,
    const _Float16* __restrict__ hB1, const float* __restrict__ hb1,
    const _Float16* __restrict__ hB2, const float* __restrict__ hb2,
    const _Float16* __restrict__ xB1, const float* __restrict__ xb1,
    const _Float16* __restrict__ xB2, const float* __restrict__ xb2,
    _Float16* __restrict__ y, float* __restrict__ xnew, int E) {
  __shared__ float hbuf[4][16 * 68];
  const int lane = threadIdx.x & 63;
  const int wv = threadIdx.x >> 6;
  const int m = lane & 15, q = lane >> 4;
  const int base = blockIdx.x * 64 + wv * 16;
  int em = base + m; if (em >= E) em = E - 1;
  const int si = src[em], di = dst[em];
  const int row = base + m;
  const bool live = row < E;

  // all gathers issued up front (incl. run-boundary dst[] for the epilogue)
  int dd[4];
  int e0 = base + q * 4;
#pragma unroll
  for (int r = 0; r < 4; ++r) {
    int e2 = e0 + r;
    dd[r] = (e2 < E) ? dst[e2] : -1;
  }
  const int node = (q < 2) ? di : si;
  const float* p = vcp + (size_t)node * 16 + (q & 1) * 8;
  float f[8];
  *(float4*)(f + 0) = *(const float4*)(p);
  *(float4*)(f + 4) = *(const float4*)(p + 4);
  const _Float16* ps = xh + (size_t)si * 64 + q * 8;
  const _Float16* pd = xh + (size_t)di * 64 + q * 8;
  U8h Xs0, Xs1, Xd0, Xd1;
  Xs0.v = *(const f16x8*)ps;         Xs1.v = *(const f16x8*)(ps + 32);
  Xd0.v = *(const f16x8*)pd;         Xd1.v = *(const f16x8*)(pd + 32);

  U8h Ah, Al;
  dec8h(f, Ah, Al);

  // hy L1 (K=32)
  f32x4 acc[4];
#pragma unroll
  for (int t = 0; t < 4; ++t) { float bv = hb1[t * 16 + m]; acc[t] = (f32x4){bv, bv, bv, bv}; }
#pragma unroll
  for (int t = 0; t < 4; ++t) {
    f16x8 b = *(const f16x8*)(hB1 + ((size_t)t * 64 + lane) * 8);
    acc[t] = __builtin_amdgcn_mfma_f32_16x16x32_f16(Ah.v, b, acc[t], 0, 0, 0);
    acc[t] = __builtin_amdgcn_mfma_f32_16x16x32_f16(Al.v, b, acc[t], 0, 0, 0);
  }

  float* hb = hbuf[wv];
#pragma unroll
  for (int t = 0; t < 4; ++t)
#pragma unroll
    for (int r = 0; r < 4; ++r)
      hb[(q * 4 + r) * 68 + t * 16 + m] = fmaxf(acc[t][r], 0.f);

  float fh[16];
  load_row(hb + m * 68 + q * 8, fh);
  U8h H0, H1;
  conv8_rne(fh + 0, H0);
  conv8_rne(fh + 8, H1);

  // hy L2 (single fp16 h)
  f32x4 o[4];
#pragma unroll
  for (int t = 0; t < 4; ++t) { float bv = hb2[t * 16 + m]; o[t] = (f32x4){bv, bv, bv, bv}; }
#pragma unroll
  for (int t = 0; t < 4; ++t) {
    f16x8 b0 = *(const f16x8*)(hB2 + ((size_t)(0 * 4 + t) * 64 + lane) * 8);
    f16x8 b1_ = *(const f16x8*)(hB2 + ((size_t)(1 * 4 + t) * 64 + lane) * 8);
    o[t] = __builtin_amdgcn_mfma_f32_16x16x32_f16(H0.v, b0, o[t], 0, 0, 0);
    o[t] = __builtin_amdgcn_mfma_f32_16x16x32_f16(H1.v, b1_, o[t], 0, 0, 0);
  }

  // transpose y0 -> row layout, quantize RNE, store + keep A-frags
#pragma unroll
  for (int t = 0; t < 4; ++t)
#pragma unroll
    for (int r = 0; r < 4; ++r)
      hb[(q * 4 + r) * 68 + t * 16 + m] = o[t][r];

  float nv[16];
  load_row(hb + m * 68 + q * 8, nv);
  U8h Yh0, Yh1;
  conv8_rne(nv + 0, Yh0);
  conv8_rne(nv + 8, Yh1);
  if (live) {
    size_t yo = (size_t)row * 64 + q * 8;
    *(f16x8*)(y + yo)      = Yh0.v;
    *(f16x8*)(y + yo + 32) = Yh1.v;
  }

  // fx L1: [xs0,xs1,xd0,xd1,y0,y1] all single fp16
  f32x4 acc2[4];
#pragma unroll
  for (int t = 0; t < 4; ++t) { float bv = xb1[t * 16 + m]; acc2[t] = (f32x4){bv, bv, bv, bv}; }
#pragma unroll
  for (int t = 0; t < 4; ++t) {
    f16x8 b0 = *(const f16x8*)(xB1 + ((size_t)(0 * 4 + t) * 64 + lane) * 8);
    f16x8 b1_ = *(const f16x8*)(xB1 + ((size_t)(1 * 4 + t) * 64 + lane) * 8);
    f16x8 b2_ = *(const f16x8*)(xB1 + ((size_t)(2 * 4 + t) * 64 + lane) * 8);
    f16x8 b3_ = *(const f16x8*)(xB1 + ((size_t)(3 * 4 + t) * 64 + lane) * 8);
    f16x8 b4_ = *(const f16x8*)(xB1 + ((size_t)(4 * 4 + t) * 64 + lane) * 8);
    f16x8 b5_ = *(const f16x8*)(xB1 + ((size_t)(5 * 4 + t) * 64 + lane) * 8);
    acc2[t] = __builtin_amdgcn_mfma_f32_16x16x32_f16(Xs0.v, b0, acc2[t], 0, 0, 0);
    acc2[t] = __builtin_amdgcn_mfma_f32_16x16x32_f16(Xs1.v, b1_, acc2[t], 0, 0, 0);
    acc2[t] = __builtin_amdgcn_mfma_f32_16x16x32_f16(Xd0.v, b2_, acc2[t], 0, 0, 0);
    acc2[t] = __builtin_amdgcn_mfma_f32_16x16x32_f16(Xd1.v, b3_, acc2[t], 0, 0, 0);
    acc2[t] = __builtin_amdgcn_mfma_f32_16x16x32_f16(Yh0.v, b4_, acc2[t], 0, 0, 0);
    acc2[t] = __builtin_amdgcn_mfma_f32_16x16x32_f16(Yh1.v, b5_, acc2[t], 0, 0, 0);
  }

#pragma unroll
  for (int t = 0; t < 4; ++t)
#pragma unroll
    for (int r = 0; r < 4; ++r)
      hb[(q * 4 + r) * 68 + t * 16 + m] = fmaxf(acc2[t][r], 0.f);

  float fh2[16];
  load_row(hb + m * 68 + q * 8, fh2);
  U8h G0, G1;
  conv8_rne(fh2 + 0, G0);
  conv8_rne(fh2 + 8, G1);

  f32x4 o2[4];
#pragma unroll
  for (int t = 0; t < 4; ++t) { float bv = xb2[t * 16 + m]; o2[t] = (f32x4){bv, bv, bv, bv}; }
#pragma unroll
  for (int t = 0; t < 4; ++t) {
    f16x8 b0 = *(const f16x8*)(xB2 + ((size_t)(0 * 4 + t) * 64 + lane) * 8);
    f16x8 b1_ = *(const f16x8*)(xB2 + ((size_t)(1 * 4 + t) * 64 + lane) * 8);
    o2[t] = __builtin_amdgcn_mfma_f32_16x16x32_f16(G0.v, b0, o2[t], 0, 0, 0);
    o2[t] = __builtin_amdgcn_mfma_f32_16x16x32_f16(G1.v, b1_, o2[t], 0, 0, 0);
  }

  RunCtx rc = run_ctx(dd, lane, q);
#pragma unroll
  for (int t = 0; t < 4; ++t) emit_t(o2[t], dd, rc, lane, m, t, xnew);
}

// ---------------- fused fy + fx (t=1,2): x and y gathered fp16 ----------------
__global__ __launch_bounds__(256) void k_fyfx(
    const _Float16* __restrict__ xh, _Float16* __restrict__ y,
    const int* __restrict__ src, const int* __restrict__ dst,
    const _Float16* __restrict__ yB1, const float* __restrict__ yb1,
    const _Float16* __restrict__ yB2, const float* __restrict__ yb2,
    const _Float16* __restrict__ xB1, const float* __restrict__ xb1,
    const _Float16* __restrict__ xB2, const float* __restrict__ xb2,
    float* __restrict__ xnew, int E, int storeY) {
  __shared__ float hbuf[4][16 * 68];
  const int lane = threadIdx.x & 63;
  const int wv = threadIdx.x >> 6;
  const int m = lane & 15, q = lane >> 4;
  const int base = blockIdx.x * 64 + wv * 16;
  int em = base + m; if (em >= E) em = E - 1;
  const int si = src[em], di = dst[em];
  const int row = base + m;
  const bool live = row < E;

  // all gathers issued up front (incl. run-boundary dst[] for the epilogue)
  int dd[4];
  int e0 = base + q * 4;
#pragma unroll
  for (int r = 0; r < 4; ++r) {
    int e2 = e0 + r;
    dd[r] = (e2 < E) ? dst[e2] : -1;
  }
  const _Float16* ps = xh + (size_t)si * 64 + q * 8;
  const _Float16* pd = xh + (size_t)di * 64 + q * 8;
  U8h Xs0, Xs1, Xd0, Xd1;
  Xs0.v = *(const f16x8*)ps;         Xs1.v = *(const f16x8*)(ps + 32);
  Xd0.v = *(const f16x8*)pd;         Xd1.v = *(const f16x8*)(pd + 32);
  U8h Ho0, Ho1;
  {
    size_t yo = (size_t)em * 64 + q * 8;
    Ho0.v = *(const f16x8*)(y + yo);  Ho1.v = *(const f16x8*)(y + yo + 32);
  }

  // fy L1: chunks [xd0,xd1,xs0,xs1] single fp16
  f32x4 acc[4];
#pragma unroll
  for (int t = 0; t < 4; ++t) { float bv = yb1[t * 16 + m]; acc[t] = (f32x4){bv, bv, bv, bv}; }
#pragma unroll
  for (int t = 0; t < 4; ++t) {
    f16x8 b0 = *(const f16x8*)(yB1 + ((size_t)(0 * 4 + t) * 64 + lane) * 8);
    f16x8 b1_ = *(const f16x8*)(yB1 + ((size_t)(1 * 4 + t) * 64 + lane) * 8);
    f16x8 b2_ = *(const f16x8*)(yB1 + ((size_t)(2 * 4 + t) * 64 + lane) * 8);
    f16x8 b3_ = *(const f16x8*)(yB1 + ((size_t)(3 * 4 + t) * 64 + lane) * 8);
    acc[t] = __builtin_amdgcn_mfma_f32_16x16x32_f16(Xd0.v, b0, acc[t], 0, 0, 0);
    acc[t] = __builtin_amdgcn_mfma_f32_16x16x32_f16(Xd1.v, b1_, acc[t], 0, 0, 0);
    acc[t] = __builtin_amdgcn_mfma_f32_16x16x32_f16(Xs0.v, b2_, acc[t], 0, 0, 0);
    acc[t] = __builtin_amdgcn_mfma_f32_16x16x32_f16(Xs1.v, b3_, acc[t], 0, 0, 0);
  }

  float* hb = hbuf[wv];
#pragma unroll
  for (int t = 0; t < 4; ++t)
#pragma unroll
    for (int r = 0; r < 4; ++r)
      hb[(q * 4 + r) * 68 + t * 16 + m] = fmaxf(acc[t][r], 0.f);

  float fh[16];
  load_row(hb + m * 68 + q * 8, fh);
  U8h H0, H1;
  conv8_rne(fh + 0, H0);
  conv8_rne(fh + 8, H1);

  // fy L2
  f32x4 o[4];
#pragma unroll
  for (int t = 0; t < 4; ++t) { float bv = yb2[t * 16 + m]; o[t] = (f32x4){bv, bv, bv, bv}; }
#pragma unroll
  for (int t = 0; t < 4; ++t) {
    f16x8 b0 = *(const f16x8*)(yB2 + ((size_t)(0 * 4 + t) * 64 + lane) * 8);
    f16x8 b1_ = *(const f16x8*)(yB2 + ((size_t)(1 * 4 + t) * 64 + lane) * 8);
    o[t] = __builtin_amdgcn_mfma_f32_16x16x32_f16(H0.v, b0, o[t], 0, 0, 0);
    o[t] = __builtin_amdgcn_mfma_f32_16x16x32_f16(H1.v, b1_, o[t], 0, 0, 0);
  }

  // transpose fy out -> row layout; y = max(y_old, out); quantize; store
#pragma unroll
  for (int t = 0; t < 4; ++t)
#pragma unroll
    for (int r = 0; r < 4; ++r)
      hb[(q * 4 + r) * 68 + t * 16 + m] = o[t][r];

  float nv[16];
  load_row(hb + m * 68 + q * 8, nv);
#pragma unroll
  for (int i = 0; i < 8; ++i) {
    nv[i]     = fmaxf((float)Ho0.s[i], nv[i]);
    nv[8 + i] = fmaxf((float)Ho1.s[i], nv[8 + i]);
  }
  U8h Yh0, Yh1;
  conv8_rne(nv + 0, Yh0);
  conv8_rne(nv + 8, Yh1);
  if (live && storeY) {
    size_t yo = (size_t)row * 64 + q * 8;
    *(f16x8*)(y + yo)      = Yh0.v;
    *(f16x8*)(y + yo + 32) = Yh1.v;
  }

  // fx L1: [xs0,xs1,xd0,xd1,y0,y1] single fp16
  f32x4 acc2[4];
#pragma unroll
  for (int t = 0; t < 4; ++t) { float bv = xb1[t * 16 + m]; acc2[t] = (f32x4){bv, bv, bv, bv}; }
#pragma unroll
  for (int t = 0; t < 4; ++t) {
    f16x8 b0 = *(const f16x8*)(xB1 + ((size_t)(0 * 4 + t) * 64 + lane) * 8);
    f16x8 b1_ = *(const f16x8*)(xB1 + ((size_t)(1 * 4 + t) * 64 + lane) * 8);
    f16x8 b2_ = *(const f16x8*)(xB1 + ((size_t)(2 * 4 + t) * 64 + lane) * 8);
    f16x8 b3_ = *(const f16x8*)(xB1 + ((size_t)(3 * 4 + t) * 64 + lane) * 8);
    f16x8 b4_ = *(const f16x8*)(xB1 + ((size_t)(4 * 4 + t) * 64 + lane) * 8);
    f16x8 b5_ = *(const f16x8*)(xB1 + ((size_t)(5 * 4 + t) * 64 + lane) * 8);
    acc2[t] = __builtin_amdgcn_mfma_f32_16x16x32_f16(Xs0.v, b0, acc2[t], 0, 0, 0);
    acc2[t] = __builtin_amdgcn_mfma_f32_16x16x32_f16(Xs1.v, b1_, acc2[t], 0, 0, 0);
    acc2[t] = __builtin_amdgcn_mfma_f32_16x16x32_f16(Xd0.v, b2_, acc2[t], 0, 0, 0);
    acc2[t] = __builtin_amdgcn_mfma_f32_16x16x32_f16(Xd1.v, b3_, acc2[t], 0, 0, 0);
    acc2[t] = __builtin_amdgcn_mfma_f32_16x16x32_f16(Yh0.v, b4_, acc2[t], 0, 0, 0);
    acc2[t] = __builtin_amdgcn_mfma_f32_16x16x32_f16(Yh1.v, b5_, acc2[t], 0, 0, 0);
  }

#pragma unroll
  for (int t = 0; t < 4; ++t)
#pragma unroll
    for (int r = 0; r < 4; ++r)
      hb[(q * 4 + r) * 68 + t * 16 + m] = fmaxf(acc2[t][r], 0.f);

  float fh2[16];
  load_row(hb + m * 68 + q * 8, fh2);
  U8h G0, G1;
  conv8_rne(fh2 + 0, G0);
  conv8_rne(fh2 + 8, G1);

  f32x4 o2[4];
#pragma unroll
  for (int t = 0; t < 4; ++t) { float bv = xb2[t * 16 + m]; o2[t] = (f32x4){bv, bv, bv, bv}; }
#pragma unroll
  for (int t = 0; t < 4; ++t) {
    f16x8 b0 = *(const f16x8*)(xB2 + ((size_t)(0 * 4 + t) * 64 + lane) * 8);
    f16x8 b1_ = *(const f16x8*)(xB2 + ((size_t)(1 * 4 + t) * 64 + lane) * 8);
    o2[t] = __builtin_amdgcn_mfma_f32_16x16x32_f16(G0.v, b0, o2[t], 0, 0, 0);
    o2[t] = __builtin_amdgcn_mfma_f32_16x16x32_f16(G1.v, b1_, o2[t], 0, 0, 0);
  }

  RunCtx rc = run_ctx(dd, lane, q);
#pragma unroll
  for (int t = 0; t < 4; ++t) emit_t(o2[t], dd, rc, lane, m, t, xnew);
}

// ---------------- feta (MFMA): out = w3 . relu(MLP2(x)) ----------------
__global__ __launch_bounds__(256) void k_feta2(
    const float* __restrict__ x,
    const _Float16* __restrict__ B1, const float* __restrict__ b1,
    const _Float16* __restrict__ B2, const float* __restrict__ b2,
    const float* __restrict__ w3, float* __restrict__ out, int N) {
  __shared__ float hbuf[4][16 * 68];
  const int lane = threadIdx.x & 63;
  const int wv = threadIdx.x >> 6;
  const int m = lane & 15, q = lane >> 4;
  const int base = blockIdx.x * 64 + wv * 16;
  int node = base + m; if (node >= N) node = N - 1;
  float fs[16];
  load_row(x + (size_t)node * 64 + q * 8, fs);
  U8h Ah[2], Al[2];
  dec8h(fs + 0, Ah[0], Al[0]);
  dec8h(fs + 8, Ah[1], Al[1]);

  f32x4 acc[4];
#pragma unroll
  for (int t = 0; t < 4; ++t) { float bv = b1[t * 16 + m]; acc[t] = (f32x4){bv, bv, bv, bv}; }
#pragma unroll
  for (int c = 0; c < 2; ++c) {
#pragma unroll
    for (int t = 0; t < 4; ++t) {
      f16x8 b = *(const f16x8*)(B1 + ((size_t)(c * 4 + t) * 64 + lane) * 8);
      acc[t] = __builtin_amdgcn_mfma_f32_16x16x32_f16(Ah[c].v, b, acc[t], 0, 0, 0);
      acc[t] = __builtin_amdgcn_mfma_f32_16x16x32_f16(Al[c].v, b, acc[t], 0, 0, 0);
    }
  }

  float* hb = hbuf[wv];
#pragma unroll
  for (int t = 0; t < 4; ++t)
#pragma unroll
    for (int r = 0; r < 4; ++r)
      hb[(q * 4 + r) * 68 + t * 16 + m] = fmaxf(acc[t][r], 0.f);

  float fh[16];
  load_row(hb + m * 68 + q * 8, fh);
  U8h A2h[2], A2l[2];
  dec8h(fh + 0, A2h[0], A2l[0]);
  dec8h(fh + 8, A2h[1], A2l[1]);

  f32x4 acc2[4];
#pragma unroll
  for (int t = 0; t < 4; ++t) { float bv = b2[t * 16 + m]; acc2[t] = (f32x4){bv, bv, bv, bv}; }
#pragma unroll
  for (int c = 0; c < 2; ++c) {
#pragma unroll
    for (int t = 0; t < 4; ++t) {
      f16x8 b = *(const f16x8*)(B2 + ((size_t)(c * 4 + t) * 64 + lane) * 8);
      acc2[t] = __builtin_amdgcn_mfma_f32_16x16x32_f16(A2h[c].v, b, acc2[t], 0, 0, 0);
      acc2[t] = __builtin_amdgcn_mfma_f32_16x16x32_f16(A2l[c].v, b, acc2[t], 0, 0, 0);
    }
  }

  float w3v[4];
#pragma unroll
  for (int t = 0; t < 4; ++t) w3v[t] = w3[t * 16 + m];
#pragma unroll
  for (int r = 0; r < 4; ++r) {
    float s = 0.f;
#pragma unroll
    for (int t = 0; t < 4; ++t) s += fmaxf(acc2[t][r], 0.f) * w3v[t];
    s += __shfl_xor(s, 1, 64);
    s += __shfl_xor(s, 2, 64);
    s += __shfl_xor(s, 4, 64);
    s += __shfl_xor(s, 8, 64);
    int row = base + q * 4 + r;
    if (m == 0 && row < N) out[row] = s;
  }
}

extern "C" void kernel_launch(void* const* d_in, const int* in_sizes, int n_in,
                              void* d_out, int out_size, void* d_ws, size_t ws_size,
                              hipStream_t stream) {
  const float* v      = (const float*)d_in[0];
  const float* labels = (const float*)d_in[1];
  const int*   ei     = (const int*)d_in[2];
  const float* hx_w1 = (const float*)d_in[4];
  const float* hx_b1 = (const float*)d_in[5];
  const float* hx_w2 = (const float*)d_in[6];
  const float* hx_b2 = (const float*)d_in[7];
  const float* hy_w1 = (const float*)d_in[8];
  const float* hy_b1 = (const float*)d_in[9];
  const float* hy_w2 = (const float*)d_in[10];
  const float* hy_b2 = (const float*)d_in[11];
  const float* fx_w1 = (const float*)d_in[12];
  const float* fx_b1 = (const float*)d_in[13];
  const float* fx_w2 = (const float*)d_in[14];
  const float* fx_b2 = (const float*)d_in[15];
  const float* fy_w1 = (const float*)d_in[16];
  const float* fy_b1 = (const float*)d_in[17];
  const float* fy_w2 = (const float*)d_in[18];
  const float* fy_b2 = (const float*)d_in[19];
  const float* feta_w1 = (const float*)d_in[20];
  const float* feta_b1 = (const float*)d_in[21];
  const float* feta_w2 = (const float*)d_in[22];
  const float* feta_b2 = (const float*)d_in[23];
  const float* feta_w3 = (const float*)d_in[24];

  int N = in_sizes[0] / 7;
  int E = in_sizes[2] / 2;
  const int* src = ei;
  const int* dst = ei + E;

  char* wsb = (char*)d_ws;
  float* goal = (float*)wsb;                                     // 16 f
  u64* goalkey = (u64*)(wsb + 64);
  float* b1p = (float*)(wsb + 96);                               // 64 f
  float* xa = (float*)(wsb + 512);                               // N*64 f
  float* xb = xa + (size_t)N * 64;                               // N*64 f
  _Float16* xh = (_Float16*)(xb + (size_t)N * 64);               // N*64 f16 gather shadow
  _Float16* y = xh + (size_t)N * 64;                             // E*64 f16
  _Float16* wp = y + (size_t)E * 64;                             // 49152 f16
  float* vcp = (float*)(wp + 49152);                             // N*16 f
  int* deg = (int*)(vcp + (size_t)N * 16);                       // N
  int* cursor = deg + N;                                         // N
  int* srcp = cursor + N;                                        // E
  int* dstp = srcp + E;                                          // E
  int* bsum = dstp + E;                                          // 64

  _Float16* fxB1 = wp;          _Float16* fxB2 = wp + 12288;
  _Float16* fyB1 = wp + 16384;  _Float16* fyB2 = wp + 24576;
  _Float16* hyB1 = wp + 28672;  _Float16* hyB2 = wp + 30720;
  _Float16* hxB1 = wp + 34816;  _Float16* hxB2 = wp + 36864;
  _Float16* feB1 = wp + 40960;  _Float16* feB2 = wp + 45056;

  int SB = (N + 1023) / 1024;

  hipMemsetAsync(deg, 0, (size_t)N * 4, stream);
  k_prep<<<24, 256, 0, stream>>>(fx_w1, fx_w2, fy_w1, fy_w2, hy_w1, hy_w2,
                                 hx_w1, hx_w2, feta_w1, feta_w2, wp, goalkey);
  k_vch<<<(N * 16 + 255) / 256, 256, 0, stream>>>(v, labels, vcp, N, dst, E, deg, goalkey);
  k_goal2b<<<1, 64, 0, stream>>>(v, labels, goalkey, hx_w1, hx_b1, goal, b1p);
  k_scan1<<<SB, 256, 0, stream>>>(deg, N, bsum);
  k_scan3<<<SB, 256, 0, stream>>>(deg, bsum, N, cursor);
  k_scatter<<<(E + 255) / 256, 256, 0, stream>>>(src, dst, E, cursor, srcp, dstp);

  // x1 -> xa (working) + xb (t=0 atomic seed) + xh (fp16 gather shadow)
  k_hx2<<<(N + 63) / 64, 256, 0, stream>>>(vcp, goal, hxB1, b1p, hxB2, hx_b2, xa, xb, xh, N);

  int EB = (E + 63) / 64;
  // t=0: y0 = hy(vcp); x2 = max(x1, agg fx(x1,y0)) -> xb
  k_hyfx<<<EB, 256, 0, stream>>>(vcp, xh, srcp, dstp,
                                 hyB1, hy_b1, hyB2, hy_b2,
                                 fxB1, fx_b1, fxB2, fx_b2, y, xb, E);
  // t=1
  k_cc<<<(N * 16 + 255) / 256, 256, 0, stream>>>((const float4*)xb, (float4*)xa, xh, N * 16);
  k_fyfx<<<EB, 256, 0, stream>>>(xh, y, srcp, dstp,
                                 fyB1, fy_b1, fyB2, fy_b2,
                                 fxB1, fx_b1, fxB2, fx_b2, xa, E, 1);
  // t=2 (y dead after: skip its store)
  k_cc<<<(N * 16 + 255) / 256, 256, 0, stream>>>((const float4*)xa, (float4*)xb, xh, N * 16);
  k_fyfx<<<EB, 256, 0, stream>>>(xh, y, srcp, dstp,
                                 fyB1, fy_b1, fyB2, fy_b2,
                                 fxB1, fx_b1, fxB2, fx_b2, xb, E, 0);

  k_feta2<<<(N + 63) / 64, 256, 0, stream>>>(xb, feB1, feta_b1, feB2, feta_b2, feta_w3,
                                             (float*)d_out, N);
}

// Round 14
// 335.951 us; speedup vs baseline: 1.0832x; 1.0188x over previous
//
#include <hip/hip_runtime.h>
#include <math.h>

typedef unsigned short u16;
typedef unsigned int u32;
typedef unsigned long long u64;
typedef __attribute__((ext_vector_type(8))) _Float16 f16x8;
typedef __attribute__((ext_vector_type(2))) _Float16 f16x2;
typedef __attribute__((ext_vector_type(4))) float f32x4;

union U8h { f16x8 v; f16x2 p[4]; u32 u[4]; _Float16 s[8]; };
union U4h { _Float16 s[4]; u64 u; };

__device__ __forceinline__ void atomicMaxF(float* addr, float val) {
  if (val >= 0.0f) {
    atomicMax((int*)addr, __float_as_int(val));
  } else {
    atomicMin((unsigned int*)addr, (unsigned int)__float_as_int(val));
  }
}

__device__ __forceinline__ f16x2 pk(float a, float b) {
  return __builtin_bit_cast(f16x2, __builtin_amdgcn_cvt_pkrtz(a, b));
}

// split 8 fp32 -> fp16 hi (RTZ) + lo (residual): hi+lo exact to ~2^-22
__device__ __forceinline__ void dec8h(const float* f, U8h& h, U8h& l) {
#pragma unroll
  for (int i = 0; i < 4; ++i) {
    float a = f[2 * i], b = f[2 * i + 1];
    f16x2 hp = pk(a, b);
    float ra = a - (float)hp[0];
    float rb = b - (float)hp[1];
    h.p[i] = hp;
    l.p[i] = pk(ra, rb);
  }
}

__device__ __forceinline__ void conv8_rne(const float* f, U8h& h) {
#pragma unroll
  for (int i = 0; i < 8; ++i) h.s[i] = (_Float16)f[i];
}

// lane's two 8-float chunks of a 64-float row (cols q*8.. and 32+q*8..)
__device__ __forceinline__ void load_row(const float* p, float* f) {
  *(float4*)(f + 0)  = *(const float4*)(p);
  *(float4*)(f + 4)  = *(const float4*)(p + 4);
  *(float4*)(f + 8)  = *(const float4*)(p + 32);
  *(float4*)(f + 12) = *(const float4*)(p + 36);
}

// ---- cross-q segmented-run merge for dst-sorted scatter-max ----
struct RunCtx { bool chain1, chain2, chain3, suppress; };

__device__ __forceinline__ RunCtx run_ctx(const int dd[4], int lane, int q) {
  bool allsame = (dd[0] == dd[1]) && (dd[1] == dd[2]) && (dd[2] == dd[3]);
  int nfd1 = __shfl(dd[0], lane + 16, 64);
  int nfd2 = __shfl(dd[0], lane + 32, 64);
  int nfd3 = __shfl(dd[0], lane + 48, 64);
  int as = allsame ? 1 : 0;
  int nas1 = __shfl(as, lane + 16, 64);
  int nas2 = __shfl(as, lane + 32, 64);
  int pld = __shfl(dd[3], lane - 16, 64);
  RunCtx c;
  c.chain1 = (q < 3) && (nfd1 == dd[3]);
  c.chain2 = c.chain1 && (nas1 != 0) && (q < 2) && (nfd2 == dd[3]);
  c.chain3 = c.chain2 && (nas2 != 0) && (q < 1) && (nfd3 == dd[3]);
  c.suppress = (q > 0) && (pld == dd[0]);
  return c;
}

__device__ __forceinline__ void emit_t(const f32x4 o, const int dd[4], const RunCtx c,
                                       int lane, int m, int t, float* __restrict__ xnew) {
  float fv = o[0];
  bool c01 = dd[1] == dd[0];
  fv = c01 ? fmaxf(fv, o[1]) : fv;
  bool c012 = c01 && (dd[2] == dd[1]);
  fv = c012 ? fmaxf(fv, o[2]) : fv;
  bool c0123 = c012 && (dd[3] == dd[2]);
  fv = c0123 ? fmaxf(fv, o[3]) : fv;
  float nfv1 = __shfl(fv, lane + 16, 64);
  float nfv2 = __shfl(fv, lane + 32, 64);
  float nfv3 = __shfl(fv, lane + 48, 64);
  float run = o[0];
  bool first = true;
#pragma unroll
  for (int r = 0; r < 4; ++r) {
    if (r > 0) run = (dd[r] == dd[r - 1]) ? fmaxf(run, o[r]) : o[r];
    bool end = (r == 3) || (dd[r + 1] != dd[r]);
    if (end) {
      float val = run;
      if (r == 3) {
        if (c.chain1) val = fmaxf(val, nfv1);
        if (c.chain2) val = fmaxf(val, nfv2);
        if (c.chain3) val = fmaxf(val, nfv3);
      }
      if (!(first && c.suppress) && dd[r] >= 0)
        atomicMaxF(&xnew[(size_t)dd[r] * 64 + t * 16 + m], val);
      first = false;
    }
  }
}

// ---------------- vcp build + degree histogram + goal argmax (fused) ----------------
__global__ __launch_bounds__(256) void k_vch(const float* __restrict__ v,
                                             const float* __restrict__ labels,
                                             float* __restrict__ vcp, int N,
                                             const int* __restrict__ dst, int E,
                                             int* __restrict__ deg, u64* __restrict__ key) {
  int tid = blockIdx.x * 256 + threadIdx.x;
  if (tid < N * 16) {
    int n = tid >> 4, c = tid & 15;
    float val = 0.f;
    if (c < 7) val = v[(size_t)n * 7 + c];
    else if (c == 7) val = labels[2 * (size_t)n];
    else if (c == 8) val = labels[2 * (size_t)n + 1];
    vcp[tid] = val;
  }
  if (tid < E) atomicAdd(&deg[dst[tid]], 1);
  if ((tid & ~63) < N) {
    float val = (tid < N) ? labels[2 * (size_t)tid + 1] : 0.0f;
    u64 k = ((u64)__float_as_uint(fmaxf(val, 0.0f)) << 32) | (u32)(~(u32)tid);
#pragma unroll
    for (int off = 32; off > 0; off >>= 1) {
      u64 o = __shfl_xor(k, off, 64);
      if (o > k) k = o;
    }
    if ((threadIdx.x & 63) == 0) atomicMax(key, k);
  }
}

// ---------------- weight prep (+ deg/goalkey zero init) ----------------
__global__ __launch_bounds__(256) void k_prep(const float* __restrict__ fxw1, const float* __restrict__ fxw2,
                                              const float* __restrict__ fyw1, const float* __restrict__ fyw2,
                                              const float* __restrict__ hyw1, const float* __restrict__ hyw2,
                                              const float* __restrict__ hxw1, const float* __restrict__ hxw2,
                                              const float* __restrict__ few1, const float* __restrict__ few2,
                                              _Float16* __restrict__ wp, u64* __restrict__ goalkey,
                                              int* __restrict__ deg, int N) {
  int tid = blockIdx.x * 256 + threadIdx.x;
  if (tid == 0) *goalkey = 0;
  for (int i = tid; i < N; i += gridDim.x * 256) deg[i] = 0;
  _Float16* fxB1 = wp;           // 12288
  _Float16* fxB2 = wp + 12288;   // 4096
  _Float16* fyB1 = wp + 16384;   // 8192
  _Float16* fyB2 = wp + 24576;   // 4096
  _Float16* hyB1 = wp + 28672;   // 2048
  _Float16* hyB2 = wp + 30720;   // 4096
  _Float16* hxB1 = wp + 34816;   // 2048
  _Float16* hxB2 = wp + 36864;   // 4096
  _Float16* feB1 = wp + 40960;   // 4096
  _Float16* feB2 = wp + 45056;   // 4096
  int which, id;
  _Float16* oh;
  if (tid < 1536)      { which = 0; id = tid;        oh = fxB1; }
  else if (tid < 2048) { which = 1; id = tid - 1536; oh = fxB2; }
  else if (tid < 3072) { which = 2; id = tid - 2048; oh = fyB1; }
  else if (tid < 3584) { which = 3; id = tid - 3072; oh = fyB2; }
  else if (tid < 3840) { which = 4; id = tid - 3584; oh = hyB1; }
  else if (tid < 4352) { which = 5; id = tid - 3840; oh = hyB2; }
  else if (tid < 4608) { which = 6; id = tid - 4352; oh = hxB1; }
  else if (tid < 5120) { which = 7; id = tid - 4608; oh = hxB2; }
  else if (tid < 5632) { which = 8; id = tid - 5120; oh = feB1; }
  else if (tid < 6144) { which = 9; id = tid - 5632; oh = feB2; }
  else return;
  int lane = id & 63;
  int q = lane >> 4, col = lane & 15;
  int c = id >> 8, t = (id >> 6) & 3;
#pragma unroll
  for (int j = 0; j < 8; ++j) {
    int k = c * 32 + q * 8 + j;
    int n = t * 16 + col;
    float w;
    if (which == 0) {
      w = (k < 64)  ? fxw1[k * 64 + n] + fxw1[(k + 64) * 64 + n]
        : (k < 128) ? fxw1[(k + 64) * 64 + n] - fxw1[(k - 64) * 64 + n]
                    : fxw1[(k + 64) * 64 + n];
    } else if (which == 1) {
      w = fxw2[k * 64 + n];
    } else if (which == 2) {
      w = (k < 64) ? fyw1[k * 64 + n] + fyw1[(k + 64) * 64 + n]
                   : fyw1[(k + 64) * 64 + n] - fyw1[(k - 64) * 64 + n];
    } else if (which == 3) {
      w = fyw2[k * 64 + n];
    } else if (which == 4) {
      if (k <= 8)                  w = hyw1[k * 64 + n] + hyw1[(k + 9) * 64 + n];
      else if (k >= 16 && k <= 24) w = hyw1[(k + 2) * 64 + n] - hyw1[(k - 16) * 64 + n];
      else                         w = 0.f;
    } else if (which == 5) {
      w = hyw2[k * 64 + n];
    } else if (which == 6) {
      w = (k < 9) ? hxw1[k * 64 + n] : (k < 27) ? hxw1[(k + 9) * 64 + n] : 0.f;
    } else if (which == 7) {
      w = hxw2[k * 64 + n];
    } else if (which == 8) {
      w = few1[k * 64 + n];
    } else {
      w = few2[k * 64 + n];
    }
    oh[id * 8 + j] = (_Float16)w;
  }
}

// ---------------- scan1 + goal2b merged (both depend only on k_vch) ----------------
__global__ __launch_bounds__(256) void k_scan1g(const int* __restrict__ deg, int N, int SB,
                                                int* __restrict__ bsum,
                                                const float* __restrict__ v,
                                                const float* __restrict__ labels,
                                                const u64* __restrict__ key,
                                                const float* __restrict__ hxw1,
                                                const float* __restrict__ hxb1,
                                                float* __restrict__ goal, float* __restrict__ b1p) {
  int b = blockIdx.x;
  if (b >= SB) {
    // goal extract + hx goal-folded bias (single block)
    __shared__ float g[9];
    int gi = (int)(~(u32)(*key));
    int c = threadIdx.x;
    if (c < 9) {
      float gv = (c < 7) ? v[7 * (size_t)gi + c] : labels[2 * (size_t)gi + (c - 7)];
      g[c] = gv;
      goal[c] = gv;
    }
    __syncthreads();
    if (c < 64) {
      float s = hxb1[c];
#pragma unroll
      for (int k = 0; k < 9; ++k) s += g[k] * hxw1[(9 + k) * 64 + c];
      b1p[c] = s;
    }
    return;
  }
  __shared__ int red[256];
  int s = 0;
  for (int i = threadIdx.x; i < 1024; i += 256) {
    int idx = b * 1024 + i;
    s += (idx < N) ? deg[idx] : 0;
  }
  red[threadIdx.x] = s; __syncthreads();
  for (int st = 128; st > 0; st >>= 1) {
    if (threadIdx.x < st) red[threadIdx.x] += red[threadIdx.x + st];
    __syncthreads();
  }
  if (threadIdx.x == 0) bsum[b] = red[0];
}

// ---------------- hx (MFMA) + scan3 merged ----------------
// blocks [0,NB): hx; blocks [NB,NB+SB): scan3
__global__ __launch_bounds__(256) void k_hx2s(
    const float* __restrict__ vcp, const float* __restrict__ goal,
    const _Float16* __restrict__ B1, const float* __restrict__ b1p,
    const _Float16* __restrict__ B2, const float* __restrict__ b2,
    float* __restrict__ xout, float* __restrict__ xout2, _Float16* __restrict__ xh, int N,
    const int* __restrict__ deg, const int* __restrict__ bsum, int* __restrict__ cursor, int NB) {
  if ((int)blockIdx.x >= NB) {
    // ---- scan3 ----
    __shared__ int lsum[256];
    __shared__ int bofs;
    int b = blockIdx.x - NB;
    int tid = threadIdx.x;
    if (tid == 0) {
      int a = 0;
      for (int i = 0; i < b; ++i) a += bsum[i];
      bofs = a;
    }
    int base_i = b * 1024 + tid * 4;
    int loc[4]; int s = 0;
#pragma unroll
    for (int j = 0; j < 4; ++j) {
      int vv = (base_i + j < N) ? deg[base_i + j] : 0;
      loc[j] = s; s += vv;
    }
    lsum[tid] = s; __syncthreads();
    for (int st = 1; st < 256; st <<= 1) {
      int add = (tid >= st) ? lsum[tid - st] : 0;
      __syncthreads();
      lsum[tid] += add;
      __syncthreads();
    }
    int toff = bofs + lsum[tid] - s;
#pragma unroll
    for (int j = 0; j < 4; ++j) {
      if (base_i + j < N) cursor[base_i + j] = toff + loc[j];
    }
    return;
  }
  // ---- hx ----
  __shared__ float hbuf[4][16 * 68];
  const int lane = threadIdx.x & 63;
  const int wv = threadIdx.x >> 6;
  const int m = lane & 15, q = lane >> 4;
  const int base = blockIdx.x * 64 + wv * 16;
  int node = base + m; if (node >= N) node = N - 1;
  float vc[12];
  *(float4*)(vc + 0) = *(const float4*)(vcp + (size_t)node * 16);
  *(float4*)(vc + 4) = *(const float4*)(vcp + (size_t)node * 16 + 4);
  *(float4*)(vc + 8) = *(const float4*)(vcp + (size_t)node * 16 + 8);
  float gl[9];
#pragma unroll
  for (int i = 0; i < 9; ++i) gl[i] = goal[i];
  float f[8];
#pragma unroll
  for (int j = 0; j < 8; ++j) {
    int idx = q * 8 + j;
    float val = 0.f;
    if (idx < 9) val = vc[idx];
    else if (idx < 18) val = vc[idx - 9] - gl[idx - 9];
    else if (idx < 27) { float dv = vc[idx - 18] - gl[idx - 18]; val = dv * dv; }
    f[j] = val;
  }
  U8h Ah, Al;
  dec8h(f, Ah, Al);

  f32x4 acc[4];
#pragma unroll
  for (int t = 0; t < 4; ++t) { float bv = b1p[t * 16 + m]; acc[t] = (f32x4){bv, bv, bv, bv}; }
#pragma unroll
  for (int t = 0; t < 4; ++t) {
    f16x8 b = *(const f16x8*)(B1 + ((size_t)t * 64 + lane) * 8);
    acc[t] = __builtin_amdgcn_mfma_f32_16x16x32_f16(Ah.v, b, acc[t], 0, 0, 0);
    acc[t] = __builtin_amdgcn_mfma_f32_16x16x32_f16(Al.v, b, acc[t], 0, 0, 0);
  }

  float* hb = hbuf[wv];
#pragma unroll
  for (int t = 0; t < 4; ++t)
#pragma unroll
    for (int r = 0; r < 4; ++r)
      hb[(q * 4 + r) * 68 + t * 16 + m] = fmaxf(acc[t][r], 0.f);

  float fh[16];
  load_row(hb + m * 68 + q * 8, fh);
  U8h A2h[2], A2l[2];
  dec8h(fh + 0, A2h[0], A2l[0]);
  dec8h(fh + 8, A2h[1], A2l[1]);

  f32x4 acc2[4];
#pragma unroll
  for (int t = 0; t < 4; ++t) { float bv = b2[t * 16 + m]; acc2[t] = (f32x4){bv, bv, bv, bv}; }
#pragma unroll
  for (int c = 0; c < 2; ++c) {
#pragma unroll
    for (int t = 0; t < 4; ++t) {
      f16x8 b = *(const f16x8*)(B2 + ((size_t)(c * 4 + t) * 64 + lane) * 8);
      acc2[t] = __builtin_amdgcn_mfma_f32_16x16x32_f16(A2h[c].v, b, acc2[t], 0, 0, 0);
      acc2[t] = __builtin_amdgcn_mfma_f32_16x16x32_f16(A2l[c].v, b, acc2[t], 0, 0, 0);
    }
  }

#pragma unroll
  for (int t = 0; t < 4; ++t)
#pragma unroll
    for (int r = 0; r < 4; ++r)
      hb[(q * 4 + r) * 68 + t * 16 + m] = acc2[t][r];

  int row = base + m;
  if (row < N) {
    float ov[16];
    const float* orow = hb + m * 68 + q * 16;
    *(float4*)(ov + 0)  = *(const float4*)(orow);
    *(float4*)(ov + 4)  = *(const float4*)(orow + 4);
    *(float4*)(ov + 8)  = *(const float4*)(orow + 8);
    *(float4*)(ov + 12) = *(const float4*)(orow + 12);
    float* p1 = xout + (size_t)row * 64 + q * 16;
    float* p2 = xout2 + (size_t)row * 64 + q * 16;
#pragma unroll
    for (int i = 0; i < 4; ++i) {
      *(float4*)(p1 + i * 4) = *(const float4*)(ov + i * 4);
      *(float4*)(p2 + i * 4) = *(const float4*)(ov + i * 4);
    }
    U8h X0, X1;
    conv8_rne(ov + 0, X0);
    conv8_rne(ov + 8, X1);
    *(f16x8*)(xh + (size_t)row * 64 + q * 16)     = X0.v;
    *(f16x8*)(xh + (size_t)row * 64 + q * 16 + 8) = X1.v;
  }
}

__global__ __launch_bounds__(256) void k_scatter(const int* __restrict__ src,
                                                 const int* __restrict__ dst, int E,
                                                 int* __restrict__ cursor,
                                                 int* __restrict__ srcp, int* __restrict__ dstp) {
  int e = blockIdx.x * 256 + threadIdx.x;
  if (e < E) {
    int d = dst[e];
    int pos = atomicAdd(&cursor[d], 1);
    srcp[pos] = src[e];
    dstp[pos] = d;
  }
}

// ---------------- convert-copy: fp32 seed copy + fp16 gather shadow ----------------
__global__ __launch_bounds__(256) void k_cc(const float4* __restrict__ s,
                                            float4* __restrict__ d,
                                            _Float16* __restrict__ h16, int n4) {
  int i = blockIdx.x * 256 + threadIdx.x;
  if (i < n4) {
    float4 v = s[i];
    d[i] = v;
    U4h o;
    o.s[0] = (_Float16)v.x; o.s[1] = (_Float16)v.y;
    o.s[2] = (_Float16)v.z; o.s[3] = (_Float16)v.w;
    *(u64*)(h16 + (size_t)i * 4) = o.u;
  }
}

// ---------------- fused hy + fx (t=0): x gathered fp16 ----------------
__global__ __launch_bounds__(256) void k_hyfx(
    const float* __restrict__ vcp, const _Float16* __restrict__ xh,
    const int* __restrict__ src, const int* __restrict__ dst,
    const _Float16* __restrict__ hB1, const float* __restrict__ hb1,
    const _Float16* __restrict__ hB2, const float* __restrict__ hb2,
    const _Float16* __restrict__ xB1, const float* __restrict__ xb1,
    const _Float16* __restrict__ xB2, const float* __restrict__ xb2,
    _Float16* __restrict__ y, float* __restrict__ xnew, int E) {
  __shared__ float hbuf[4][16 * 68];
  const int lane = threadIdx.x & 63;
  const int wv = threadIdx.x >> 6;
  const int m = lane & 15, q = lane >> 4;
  const int base = blockIdx.x * 64 + wv * 16;
  int em = base + m; if (em >= E) em = E - 1;
  const int si = src[em], di = dst[em];
  const int row = base + m;
  const bool live = row < E;

  int dd[4];
  int e0 = base + q * 4;
#pragma unroll
  for (int r = 0; r < 4; ++r) {
    int e2 = e0 + r;
    dd[r] = (e2 < E) ? dst[e2] : -1;
  }
  const int node = (q < 2) ? di : si;
  const float* p = vcp + (size_t)node * 16 + (q & 1) * 8;
  float f[8];
  *(float4*)(f + 0) = *(const float4*)(p);
  *(float4*)(f + 4) = *(const float4*)(p + 4);
  const _Float16* ps = xh + (size_t)si * 64 + q * 8;
  const _Float16* pd = xh + (size_t)di * 64 + q * 8;
  U8h Xs0, Xs1, Xd0, Xd1;
  Xs0.v = *(const f16x8*)ps;         Xs1.v = *(const f16x8*)(ps + 32);
  Xd0.v = *(const f16x8*)pd;         Xd1.v = *(const f16x8*)(pd + 32);

  U8h Ah, Al;
  dec8h(f, Ah, Al);

  f32x4 acc[4];
#pragma unroll
  for (int t = 0; t < 4; ++t) { float bv = hb1[t * 16 + m]; acc[t] = (f32x4){bv, bv, bv, bv}; }
#pragma unroll
  for (int t = 0; t < 4; ++t) {
    f16x8 b = *(const f16x8*)(hB1 + ((size_t)t * 64 + lane) * 8);
    acc[t] = __builtin_amdgcn_mfma_f32_16x16x32_f16(Ah.v, b, acc[t], 0, 0, 0);
    acc[t] = __builtin_amdgcn_mfma_f32_16x16x32_f16(Al.v, b, acc[t], 0, 0, 0);
  }

  float* hb = hbuf[wv];
#pragma unroll
  for (int t = 0; t < 4; ++t)
#pragma unroll
    for (int r = 0; r < 4; ++r)
      hb[(q * 4 + r) * 68 + t * 16 + m] = fmaxf(acc[t][r], 0.f);

  float fh[16];
  load_row(hb + m * 68 + q * 8, fh);
  U8h H0, H1;
  conv8_rne(fh + 0, H0);
  conv8_rne(fh + 8, H1);

  f32x4 o[4];
#pragma unroll
  for (int t = 0; t < 4; ++t) { float bv = hb2[t * 16 + m]; o[t] = (f32x4){bv, bv, bv, bv}; }
#pragma unroll
  for (int t = 0; t < 4; ++t) {
    f16x8 b0 = *(const f16x8*)(hB2 + ((size_t)(0 * 4 + t) * 64 + lane) * 8);
    f16x8 b1_ = *(const f16x8*)(hB2 + ((size_t)(1 * 4 + t) * 64 + lane) * 8);
    o[t] = __builtin_amdgcn_mfma_f32_16x16x32_f16(H0.v, b0, o[t], 0, 0, 0);
    o[t] = __builtin_amdgcn_mfma_f32_16x16x32_f16(H1.v, b1_, o[t], 0, 0, 0);
  }

#pragma unroll
  for (int t = 0; t < 4; ++t)
#pragma unroll
    for (int r = 0; r < 4; ++r)
      hb[(q * 4 + r) * 68 + t * 16 + m] = o[t][r];

  float nv[16];
  load_row(hb + m * 68 + q * 8, nv);
  U8h Yh0, Yh1;
  conv8_rne(nv + 0, Yh0);
  conv8_rne(nv + 8, Yh1);
  if (live) {
    size_t yo = (size_t)row * 64 + q * 8;
    *(f16x8*)(y + yo)      = Yh0.v;
    *(f16x8*)(y + yo + 32) = Yh1.v;
  }

  f32x4 acc2[4];
#pragma unroll
  for (int t = 0; t < 4; ++t) { float bv = xb1[t * 16 + m]; acc2[t] = (f32x4){bv, bv, bv, bv}; }
#pragma unroll
  for (int t = 0; t < 4; ++t) {
    f16x8 b0 = *(const f16x8*)(xB1 + ((size_t)(0 * 4 + t) * 64 + lane) * 8);
    f16x8 b1_ = *(const f16x8*)(xB1 + ((size_t)(1 * 4 + t) * 64 + lane) * 8);
    f16x8 b2_ = *(const f16x8*)(xB1 + ((size_t)(2 * 4 + t) * 64 + lane) * 8);
    f16x8 b3_ = *(const f16x8*)(xB1 + ((size_t)(3 * 4 + t) * 64 + lane) * 8);
    f16x8 b4_ = *(const f16x8*)(xB1 + ((size_t)(4 * 4 + t) * 64 + lane) * 8);
    f16x8 b5_ = *(const f16x8*)(xB1 + ((size_t)(5 * 4 + t) * 64 + lane) * 8);
    acc2[t] = __builtin_amdgcn_mfma_f32_16x16x32_f16(Xs0.v, b0, acc2[t], 0, 0, 0);
    acc2[t] = __builtin_amdgcn_mfma_f32_16x16x32_f16(Xs1.v, b1_, acc2[t], 0, 0, 0);
    acc2[t] = __builtin_amdgcn_mfma_f32_16x16x32_f16(Xd0.v, b2_, acc2[t], 0, 0, 0);
    acc2[t] = __builtin_amdgcn_mfma_f32_16x16x32_f16(Xd1.v, b3_, acc2[t], 0, 0, 0);
    acc2[t] = __builtin_amdgcn_mfma_f32_16x16x32_f16(Yh0.v, b4_, acc2[t], 0, 0, 0);
    acc2[t] = __builtin_amdgcn_mfma_f32_16x16x32_f16(Yh1.v, b5_, acc2[t], 0, 0, 0);
  }

#pragma unroll
  for (int t = 0; t < 4; ++t)
#pragma unroll
    for (int r = 0; r < 4; ++r)
      hb[(q * 4 + r) * 68 + t * 16 + m] = fmaxf(acc2[t][r], 0.f);

  float fh2[16];
  load_row(hb + m * 68 + q * 8, fh2);
  U8h G0, G1;
  conv8_rne(fh2 + 0, G0);
  conv8_rne(fh2 + 8, G1);

  f32x4 o2[4];
#pragma unroll
  for (int t = 0; t < 4; ++t) { float bv = xb2[t * 16 + m]; o2[t] = (f32x4){bv, bv, bv, bv}; }
#pragma unroll
  for (int t = 0; t < 4; ++t) {
    f16x8 b0 = *(const f16x8*)(xB2 + ((size_t)(0 * 4 + t) * 64 + lane) * 8);
    f16x8 b1_ = *(const f16x8*)(xB2 + ((size_t)(1 * 4 + t) * 64 + lane) * 8);
    o2[t] = __builtin_amdgcn_mfma_f32_16x16x32_f16(G0.v, b0, o2[t], 0, 0, 0);
    o2[t] = __builtin_amdgcn_mfma_f32_16x16x32_f16(G1.v, b1_, o2[t], 0, 0, 0);
  }

  RunCtx rc = run_ctx(dd, lane, q);
#pragma unroll
  for (int t = 0; t < 4; ++t) emit_t(o2[t], dd, rc, lane, m, t, xnew);
}

// ---------------- fused fy + fx (t=1,2): x and y gathered fp16 ----------------
__global__ __launch_bounds__(256) void k_fyfx(
    const _Float16* __restrict__ xh, _Float16* __restrict__ y,
    const int* __restrict__ src, const int* __restrict__ dst,
    const _Float16* __restrict__ yB1, const float* __restrict__ yb1,
    const _Float16* __restrict__ yB2, const float* __restrict__ yb2,
    const _Float16* __restrict__ xB1, const float* __restrict__ xb1,
    const _Float16* __restrict__ xB2, const float* __restrict__ xb2,
    float* __restrict__ xnew, int E, int storeY) {
  __shared__ float hbuf[4][16 * 68];
  const int lane = threadIdx.x & 63;
  const int wv = threadIdx.x >> 6;
  const int m = lane & 15, q = lane >> 4;
  const int base = blockIdx.x * 64 + wv * 16;
  int em = base + m; if (em >= E) em = E - 1;
  const int si = src[em], di = dst[em];
  const int row = base + m;
  const bool live = row < E;

  int dd[4];
  int e0 = base + q * 4;
#pragma unroll
  for (int r = 0; r < 4; ++r) {
    int e2 = e0 + r;
    dd[r] = (e2 < E) ? dst[e2] : -1;
  }
  const _Float16* ps = xh + (size_t)si * 64 + q * 8;
  const _Float16* pd = xh + (size_t)di * 64 + q * 8;
  U8h Xs0, Xs1, Xd0, Xd1;
  Xs0.v = *(const f16x8*)ps;         Xs1.v = *(const f16x8*)(ps + 32);
  Xd0.v = *(const f16x8*)pd;         Xd1.v = *(const f16x8*)(pd + 32);
  U8h Ho0, Ho1;
  {
    size_t yo = (size_t)em * 64 + q * 8;
    Ho0.v = *(const f16x8*)(y + yo);  Ho1.v = *(const f16x8*)(y + yo + 32);
  }

  f32x4 acc[4];
#pragma unroll
  for (int t = 0; t < 4; ++t) { float bv = yb1[t * 16 + m]; acc[t] = (f32x4){bv, bv, bv, bv}; }
#pragma unroll
  for (int t = 0; t < 4; ++t) {
    f16x8 b0 = *(const f16x8*)(yB1 + ((size_t)(0 * 4 + t) * 64 + lane) * 8);
    f16x8 b1_ = *(const f16x8*)(yB1 + ((size_t)(1 * 4 + t) * 64 + lane) * 8);
    f16x8 b2_ = *(const f16x8*)(yB1 + ((size_t)(2 * 4 + t) * 64 + lane) * 8);
    f16x8 b3_ = *(const f16x8*)(yB1 + ((size_t)(3 * 4 + t) * 64 + lane) * 8);
    acc[t] = __builtin_amdgcn_mfma_f32_16x16x32_f16(Xd0.v, b0, acc[t], 0, 0, 0);
    acc[t] = __builtin_amdgcn_mfma_f32_16x16x32_f16(Xd1.v, b1_, acc[t], 0, 0, 0);
    acc[t] = __builtin_amdgcn_mfma_f32_16x16x32_f16(Xs0.v, b2_, acc[t], 0, 0, 0);
    acc[t] = __builtin_amdgcn_mfma_f32_16x16x32_f16(Xs1.v, b3_, acc[t], 0, 0, 0);
  }

  float* hb = hbuf[wv];
#pragma unroll
  for (int t = 0; t < 4; ++t)
#pragma unroll
    for (int r = 0; r < 4; ++r)
      hb[(q * 4 + r) * 68 + t * 16 + m] = fmaxf(acc[t][r], 0.f);

  float fh[16];
  load_row(hb + m * 68 + q * 8, fh);
  U8h H0, H1;
  conv8_rne(fh + 0, H0);
  conv8_rne(fh + 8, H1);

  f32x4 o[4];
#pragma unroll
  for (int t = 0; t < 4; ++t) { float bv = yb2[t * 16 + m]; o[t] = (f32x4){bv, bv, bv, bv}; }
#pragma unroll
  for (int t = 0; t < 4; ++t) {
    f16x8 b0 = *(const f16x8*)(yB2 + ((size_t)(0 * 4 + t) * 64 + lane) * 8);
    f16x8 b1_ = *(const f16x8*)(yB2 + ((size_t)(1 * 4 + t) * 64 + lane) * 8);
    o[t] = __builtin_amdgcn_mfma_f32_16x16x32_f16(H0.v, b0, o[t], 0, 0, 0);
    o[t] = __builtin_amdgcn_mfma_f32_16x16x32_f16(H1.v, b1_, o[t], 0, 0, 0);
  }

#pragma unroll
  for (int t = 0; t < 4; ++t)
#pragma unroll
    for (int r = 0; r < 4; ++r)
      hb[(q * 4 + r) * 68 + t * 16 + m] = o[t][r];

  float nv[16];
  load_row(hb + m * 68 + q * 8, nv);
#pragma unroll
  for (int i = 0; i < 8; ++i) {
    nv[i]     = fmaxf((float)Ho0.s[i], nv[i]);
    nv[8 + i] = fmaxf((float)Ho1.s[i], nv[8 + i]);
  }
  U8h Yh0, Yh1;
  conv8_rne(nv + 0, Yh0);
  conv8_rne(nv + 8, Yh1);
  if (live && storeY) {
    size_t yo = (size_t)row * 64 + q * 8;
    *(f16x8*)(y + yo)      = Yh0.v;
    *(f16x8*)(y + yo + 32) = Yh1.v;
  }

  f32x4 acc2[4];
#pragma unroll
  for (int t = 0; t < 4; ++t) { float bv = xb1[t * 16 + m]; acc2[t] = (f32x4){bv, bv, bv, bv}; }
#pragma unroll
  for (int t = 0; t < 4; ++t) {
    f16x8 b0 = *(const f16x8*)(xB1 + ((size_t)(0 * 4 + t) * 64 + lane) * 8);
    f16x8 b1_ = *(const f16x8*)(xB1 + ((size_t)(1 * 4 + t) * 64 + lane) * 8);
    f16x8 b2_ = *(const f16x8*)(xB1 + ((size_t)(2 * 4 + t) * 64 + lane) * 8);
    f16x8 b3_ = *(const f16x8*)(xB1 + ((size_t)(3 * 4 + t) * 64 + lane) * 8);
    f16x8 b4_ = *(const f16x8*)(xB1 + ((size_t)(4 * 4 + t) * 64 + lane) * 8);
    f16x8 b5_ = *(const f16x8*)(xB1 + ((size_t)(5 * 4 + t) * 64 + lane) * 8);
    acc2[t] = __builtin_amdgcn_mfma_f32_16x16x32_f16(Xs0.v, b0, acc2[t], 0, 0, 0);
    acc2[t] = __builtin_amdgcn_mfma_f32_16x16x32_f16(Xs1.v, b1_, acc2[t], 0, 0, 0);
    acc2[t] = __builtin_amdgcn_mfma_f32_16x16x32_f16(Xd0.v, b2_, acc2[t], 0, 0, 0);
    acc2[t] = __builtin_amdgcn_mfma_f32_16x16x32_f16(Xd1.v, b3_, acc2[t], 0, 0, 0);
    acc2[t] = __builtin_amdgcn_mfma_f32_16x16x32_f16(Yh0.v, b4_, acc2[t], 0, 0, 0);
    acc2[t] = __builtin_amdgcn_mfma_f32_16x16x32_f16(Yh1.v, b5_, acc2[t], 0, 0, 0);
  }

#pragma unroll
  for (int t = 0; t < 4; ++t)
#pragma unroll
    for (int r = 0; r < 4; ++r)
      hb[(q * 4 + r) * 68 + t * 16 + m] = fmaxf(acc2[t][r], 0.f);

  float fh2[16];
  load_row(hb + m * 68 + q * 8, fh2);
  U8h G0, G1;
  conv8_rne(fh2 + 0, G0);
  conv8_rne(fh2 + 8, G1);

  f32x4 o2[4];
#pragma unroll
  for (int t = 0; t < 4; ++t) { float bv = xb2[t * 16 + m]; o2[t] = (f32x4){bv, bv, bv, bv}; }
#pragma unroll
  for (int t = 0; t < 4; ++t) {
    f16x8 b0 = *(const f16x8*)(xB2 + ((size_t)(0 * 4 + t) * 64 + lane) * 8);
    f16x8 b1_ = *(const f16x8*)(xB2 + ((size_t)(1 * 4 + t) * 64 + lane) * 8);
    o2[t] = __builtin_amdgcn_mfma_f32_16x16x32_f16(G0.v, b0, o2[t], 0, 0, 0);
    o2[t] = __builtin_amdgcn_mfma_f32_16x16x32_f16(G1.v, b1_, o2[t], 0, 0, 0);
  }

  RunCtx rc = run_ctx(dd, lane, q);
#pragma unroll
  for (int t = 0; t < 4; ++t) emit_t(o2[t], dd, rc, lane, m, t, xnew);
}

// ---------------- feta (MFMA): out = w3 . relu(MLP2(x)) ----------------
__global__ __launch_bounds__(256) void k_feta2(
    const float* __restrict__ x,
    const _Float16* __restrict__ B1, const float* __restrict__ b1,
    const _Float16* __restrict__ B2, const float* __restrict__ b2,
    const float* __restrict__ w3, float* __restrict__ out, int N) {
  __shared__ float hbuf[4][16 * 68];
  const int lane = threadIdx.x & 63;
  const int wv = threadIdx.x >> 6;
  const int m = lane & 15, q = lane >> 4;
  const int base = blockIdx.x * 64 + wv * 16;
  int node = base + m; if (node >= N) node = N - 1;
  float fs[16];
  load_row(x + (size_t)node * 64 + q * 8, fs);
  U8h Ah[2], Al[2];
  dec8h(fs + 0, Ah[0], Al[0]);
  dec8h(fs + 8, Ah[1], Al[1]);

  f32x4 acc[4];
#pragma unroll
  for (int t = 0; t < 4; ++t) { float bv = b1[t * 16 + m]; acc[t] = (f32x4){bv, bv, bv, bv}; }
#pragma unroll
  for (int c = 0; c < 2; ++c) {
#pragma unroll
    for (int t = 0; t < 4; ++t) {
      f16x8 b = *(const f16x8*)(B1 + ((size_t)(c * 4 + t) * 64 + lane) * 8);
      acc[t] = __builtin_amdgcn_mfma_f32_16x16x32_f16(Ah[c].v, b, acc[t], 0, 0, 0);
      acc[t] = __builtin_amdgcn_mfma_f32_16x16x32_f16(Al[c].v, b, acc[t], 0, 0, 0);
    }
  }

  float* hb = hbuf[wv];
#pragma unroll
  for (int t = 0; t < 4; ++t)
#pragma unroll
    for (int r = 0; r < 4; ++r)
      hb[(q * 4 + r) * 68 + t * 16 + m] = fmaxf(acc[t][r], 0.f);

  float fh[16];
  load_row(hb + m * 68 + q * 8, fh);
  U8h A2h[2], A2l[2];
  dec8h(fh + 0, A2h[0], A2l[0]);
  dec8h(fh + 8, A2h[1], A2l[1]);

  f32x4 acc2[4];
#pragma unroll
  for (int t = 0; t < 4; ++t) { float bv = b2[t * 16 + m]; acc2[t] = (f32x4){bv, bv, bv, bv}; }
#pragma unroll
  for (int c = 0; c < 2; ++c) {
#pragma unroll
    for (int t = 0; t < 4; ++t) {
      f16x8 b = *(const f16x8*)(B2 + ((size_t)(c * 4 + t) * 64 + lane) * 8);
      acc2[t] = __builtin_amdgcn_mfma_f32_16x16x32_f16(A2h[c].v, b, acc2[t], 0, 0, 0);
      acc2[t] = __builtin_amdgcn_mfma_f32_16x16x32_f16(A2l[c].v, b, acc2[t], 0, 0, 0);
    }
  }

  float w3v[4];
#pragma unroll
  for (int t = 0; t < 4; ++t) w3v[t] = w3[t * 16 + m];
#pragma unroll
  for (int r = 0; r < 4; ++r) {
    float s = 0.f;
#pragma unroll
    for (int t = 0; t < 4; ++t) s += fmaxf(acc2[t][r], 0.f) * w3v[t];
    s += __shfl_xor(s, 1, 64);
    s += __shfl_xor(s, 2, 64);
    s += __shfl_xor(s, 4, 64);
    s += __shfl_xor(s, 8, 64);
    int row = base + q * 4 + r;
    if (m == 0 && row < N) out[row] = s;
  }
}

extern "C" void kernel_launch(void* const* d_in, const int* in_sizes, int n_in,
                              void* d_out, int out_size, void* d_ws, size_t ws_size,
                              hipStream_t stream) {
  const float* v      = (const float*)d_in[0];
  const float* labels = (const float*)d_in[1];
  const int*   ei     = (const int*)d_in[2];
  const float* hx_w1 = (const float*)d_in[4];
  const float* hx_b1 = (const float*)d_in[5];
  const float* hx_w2 = (const float*)d_in[6];
  const float* hx_b2 = (const float*)d_in[7];
  const float* hy_w1 = (const float*)d_in[8];
  const float* hy_b1 = (const float*)d_in[9];
  const float* hy_w2 = (const float*)d_in[10];
  const float* hy_b2 = (const float*)d_in[11];
  const float* fx_w1 = (const float*)d_in[12];
  const float* fx_b1 = (const float*)d_in[13];
  const float* fx_w2 = (const float*)d_in[14];
  const float* fx_b2 = (const float*)d_in[15];
  const float* fy_w1 = (const float*)d_in[16];
  const float* fy_b1 = (const float*)d_in[17];
  const float* fy_w2 = (const float*)d_in[18];
  const float* fy_b2 = (const float*)d_in[19];
  const float* feta_w1 = (const float*)d_in[20];
  const float* feta_b1 = (const float*)d_in[21];
  const float* feta_w2 = (const float*)d_in[22];
  const float* feta_b2 = (const float*)d_in[23];
  const float* feta_w3 = (const float*)d_in[24];

  int N = in_sizes[0] / 7;
  int E = in_sizes[2] / 2;
  const int* src = ei;
  const int* dst = ei + E;

  char* wsb = (char*)d_ws;
  float* goal = (float*)wsb;                                     // 16 f
  u64* goalkey = (u64*)(wsb + 64);
  float* b1p = (float*)(wsb + 96);                               // 64 f
  float* xa = (float*)(wsb + 512);                               // N*64 f
  float* xb = xa + (size_t)N * 64;                               // N*64 f
  _Float16* xh = (_Float16*)(xb + (size_t)N * 64);               // N*64 f16 gather shadow
  _Float16* y = xh + (size_t)N * 64;                             // E*64 f16
  _Float16* wp = y + (size_t)E * 64;                             // 49152 f16
  float* vcp = (float*)(wp + 49152);                             // N*16 f
  int* deg = (int*)(vcp + (size_t)N * 16);                       // N
  int* cursor = deg + N;                                         // N
  int* srcp = cursor + N;                                        // E
  int* dstp = srcp + E;                                          // E
  int* bsum = dstp + E;                                          // 64

  _Float16* fxB1 = wp;          _Float16* fxB2 = wp + 12288;
  _Float16* fyB1 = wp + 16384;  _Float16* fyB2 = wp + 24576;
  _Float16* hyB1 = wp + 28672;  _Float16* hyB2 = wp + 30720;
  _Float16* hxB1 = wp + 34816;  _Float16* hxB2 = wp + 36864;
  _Float16* feB1 = wp + 40960;  _Float16* feB2 = wp + 45056;

  int SB = (N + 1023) / 1024;
  int NB = (N + 63) / 64;
  int EB = (E + 63) / 64;

  // prep weights + zero deg/goalkey (one kernel, no memset)
  k_prep<<<25, 256, 0, stream>>>(fx_w1, fx_w2, fy_w1, fy_w2, hy_w1, hy_w2,
                                 hx_w1, hx_w2, feta_w1, feta_w2, wp, goalkey, deg, N);
  k_vch<<<(N * 16 + 255) / 256, 256, 0, stream>>>(v, labels, vcp, N, dst, E, deg, goalkey);
  // scan1 + goal2b (independent, merged)
  k_scan1g<<<SB + 1, 256, 0, stream>>>(deg, N, SB, bsum, v, labels, goalkey,
                                       hx_w1, hx_b1, goal, b1p);
  // hx (needs b1p) + scan3 (needs bsum) merged
  k_hx2s<<<NB + SB, 256, 0, stream>>>(vcp, goal, hxB1, b1p, hxB2, hx_b2, xa, xb, xh, N,
                                      deg, bsum, cursor, NB);
  k_scatter<<<(E + 255) / 256, 256, 0, stream>>>(src, dst, E, cursor, srcp, dstp);

  // t=0: y0 = hy(vcp); x2 = max(x1, agg fx(x1,y0)) -> xb
  k_hyfx<<<EB, 256, 0, stream>>>(vcp, xh, srcp, dstp,
                                 hyB1, hy_b1, hyB2, hy_b2,
                                 fxB1, fx_b1, fxB2, fx_b2, y, xb, E);
  // t=1
  k_cc<<<(N * 16 + 255) / 256, 256, 0, stream>>>((const float4*)xb, (float4*)xa, xh, N * 16);
  k_fyfx<<<EB, 256, 0, stream>>>(xh, y, srcp, dstp,
                                 fyB1, fy_b1, fyB2, fy_b2,
                                 fxB1, fx_b1, fxB2, fx_b2, xa, E, 1);
  // t=2 (y dead after: skip its store)
  k_cc<<<(N * 16 + 255) / 256, 256, 0, stream>>>((const float4*)xa, (float4*)xb, xh, N * 16);
  k_fyfx<<<EB, 256, 0, stream>>>(xh, y, srcp, dstp,
                                 fyB1, fy_b1, fyB2, fy_b2,
                                 fxB1, fx_b1, fxB2, fx_b2, xb, E, 0);

  k_feta2<<<NB, 256, 0, stream>>>(xb, feB1, feta_b1, feB2, feta_b2, feta_w3,
                                  (float*)d_out, N);
}